// Round 1
// baseline (892.765 us; speedup 1.0000x reference)
//
#include <hip/hip_runtime.h>
#include <cstdint>
#include <cstddef>

// CENET fused pipeline for MI355X (gfx950).
// Workspace requirement: ~151 MB (see offsets in kernel_launch).

typedef unsigned short u16;
typedef __attribute__((ext_vector_type(8))) short short8;
typedef __attribute__((ext_vector_type(4))) float f32x4;

__device__ __forceinline__ f32x4 mfma16(short8 a, short8 b, f32x4 c){
  return __builtin_amdgcn_mfma_f32_16x16x32_bf16(a, b, c, 0, 0, 0);
}
__device__ __forceinline__ float bf2f(u16 u){
  unsigned v = ((unsigned)u) << 16; float f; __builtin_memcpy(&f, &v, 4); return f;
}
__device__ __forceinline__ u16 f2bf(float f){
  unsigned u; __builtin_memcpy(&u, &f, 4);
  u += 0x7FFFu + ((u >> 16) & 1u);            // round-to-nearest-even
  return (u16)(u >> 16);
}
__device__ __forceinline__ float sigf(float x){ return 1.f / (1.f + __expf(-x)); }

// ---------------- fp32 -> zero-padded bf16 conversion (all weights in one dispatch) ----
struct CvtD { const float* s; u16* d; int M, K, Mp, Kp; };
struct CvtTab { CvtD t[10]; };

__global__ void cvt_all(CvtTab tab){
  CvtD de = tab.t[blockIdx.y];
  int total = de.Mp * de.Kp;
  for (int i = blockIdx.x * blockDim.x + threadIdx.x; i < total; i += gridDim.x * blockDim.x){
    int r = i / de.Kp, c = i - r * de.Kp;
    float v = (r < de.M && c < de.K) ? de.s[(size_t)r * de.K + c] : 0.f;
    de.d[i] = f2bf(v);
  }
}

__global__ void init_out(float* o){ if (threadIdx.x < 2) o[threadIdx.x] = 0.f; }

// mapped_rel (460,200) fp32 -> transposed bf16 (256,512) zero-padded
__global__ void transpose_mrel(const float* __restrict__ m32, u16* __restrict__ mT){
  int i = blockIdx.x * blockDim.x + threadIdx.x;       // 256*512
  if (i < 256 * 512){
    int n = i >> 9, r = i & 511;
    float v = (n < 200 && r < 460) ? m32[r * 200 + n] : 0.f;
    mT[i] = f2bf(v);
  }
}

// q_rel gather: bf16 row copy + fp32 copy
__global__ void gather_qrel(const u16* __restrict__ mbf, const float* __restrict__ m32,
                            const int* __restrict__ trip, u16* __restrict__ qbf,
                            float* __restrict__ q32){
  int i = blockIdx.x * blockDim.x + threadIdx.x;       // 2048*256
  if (i < 2048 * 256){
    int b = i >> 8, c = i & 255;
    int rel = trip[b * 3 + 1];
    qbf[i] = mbf[rel * 256 + c];
    if (c < 200) q32[b * 200 + c] = m32[rel * 200 + c];
  }
}

// ---------------- generic MFMA GEMM: C = A(M,K) @ B(N,K)^T + bias ----------------
// A (lda = padded K), B (ldb = padded K), both bf16 zero-padded; 128x128 tile, BK=64.
// MODE 0: optional fp32 C (ld=Nreal) and/or bf16 C (ld=ldc16, zero-pad col>=Nreal)
// MODE 1: predicted_hist epilogue: pv = 0.1*(acc+bias) + extra[row,col]; fp32+bf16
// MODE 2: score epilogue: sigmoid -> C32[2 + row*Nreal + col], path-loss atomic to loss
template<int MODE>
__global__ __launch_bounds__(256) void gemm_bt(
    const u16* __restrict__ A, int lda,
    const u16* __restrict__ B, int ldb,
    int K, int Mreal, int Nreal,
    const float* __restrict__ bias,
    float* __restrict__ C32,
    u16* __restrict__ C16, int ldc16,
    const float* __restrict__ extra,
    const int* __restrict__ trip,
    float* __restrict__ loss)
{
  __shared__ u16 As[128 * 64];
  __shared__ u16 Bs[128 * 64];
  __shared__ float red[256];
  const int tid = threadIdx.x;
  const int wave = tid >> 6, lane = tid & 63;
  const int m0 = blockIdx.y * 128, n0 = blockIdx.x * 128;
  const int wm = (wave >> 1) * 64, wn = (wave & 1) * 64;
  const int lr = lane >> 3, lc = (lane & 7) * 8;   // staging: 8 rows x 64 cols per 1KB chunk
  const int fr = lane & 15, fk = (lane >> 4) * 8;  // fragment row/col & k-offset

  f32x4 acc[4][4];
  #pragma unroll
  for (int i = 0; i < 4; ++i)
    #pragma unroll
    for (int j = 0; j < 4; ++j) acc[i][j] = (f32x4){0.f, 0.f, 0.f, 0.f};

  const int kT = (K + 63) >> 6;
  for (int kt = 0; kt < kT; ++kt){
    #pragma unroll
    for (int i = 0; i < 4; ++i){
      int ch = wave * 4 + i;
      const u16* ga = A + (size_t)(m0 + ch * 8 + lr) * lda + kt * 64 + lc;
      __builtin_amdgcn_global_load_lds((const __attribute__((address_space(1))) void*)ga,
          (__attribute__((address_space(3))) void*)(As + ch * 512), 16, 0, 0);
      const u16* gb = B + (size_t)(n0 + ch * 8 + lr) * ldb + kt * 64 + lc;
      __builtin_amdgcn_global_load_lds((const __attribute__((address_space(1))) void*)gb,
          (__attribute__((address_space(3))) void*)(Bs + ch * 512), 16, 0, 0);
    }
    __syncthreads();
    #pragma unroll
    for (int ks = 0; ks < 2; ++ks){
      short8 av[4], bv[4];
      #pragma unroll
      for (int i = 0; i < 4; ++i){
        av[i] = *(const short8*)(As + (wm + i * 16 + fr) * 64 + ks * 32 + fk);
        bv[i] = *(const short8*)(Bs + (wn + i * 16 + fr) * 64 + ks * 32 + fk);
      }
      #pragma unroll
      for (int i = 0; i < 4; ++i)
        #pragma unroll
        for (int j = 0; j < 4; ++j)
          acc[i][j] = mfma16(av[i], bv[j], acc[i][j]);
    }
    __syncthreads();
  }

  float lsum = 0.f;
  #pragma unroll
  for (int i = 0; i < 4; ++i){
    #pragma unroll
    for (int j = 0; j < 4; ++j){
      int col = n0 + wn + j * 16 + fr;
      float bvl = 0.f;
      if (bias && col < Nreal) bvl = bias[col];
      #pragma unroll
      for (int r = 0; r < 4; ++r){
        int row = m0 + wm + i * 16 + (lane >> 4) * 4 + r;
        float v = acc[i][j][r] + bvl;
        if (MODE == 0){
          if (C32 && row < Mreal && col < Nreal) C32[(size_t)row * Nreal + col] = v;
          if (C16) C16[(size_t)row * ldc16 + col] =
              (row < Mreal && col < Nreal) ? f2bf(v) : (u16)0;
        } else if (MODE == 1){
          if (row < Mreal){
            if (col < Nreal){
              float pv = 0.1f * v + extra[(size_t)row * Nreal + col];
              C32[(size_t)row * Nreal + col] = pv;
              C16[(size_t)row * ldc16 + col] = f2bf(pv);
            } else {
              C16[(size_t)row * ldc16 + col] = 0;
            }
          }
        } else {
          if (row < Mreal && col < Nreal){
            C32[2 + (size_t)row * Nreal + col] = sigf(v);
            float x = (trip[row * 3 + 2] == col) ? v : -v;     // label select
            lsum += fminf(x, 0.f) - log1pf(__expf(-fabsf(x))); // log_sigmoid(x)
          }
        }
      }
    }
  }
  if (MODE == 2){
    red[tid] = lsum;
    __syncthreads();
    for (int s = 128; s > 0; s >>= 1){
      if (tid < s) red[tid] += red[tid + s];
      __syncthreads();
    }
    if (tid == 0) atomicAdd(loss, -red[0] * (1.f / 20480000.f));
  }
}

// ---------------- masked softmax over R=460, one wave per (t,b) row -------------------
__global__ __launch_bounds__(256) void softmax_k(
    const float* __restrict__ part, const float* __restrict__ base,
    int t0, u16* __restrict__ aout)
{
  int wave = threadIdx.x >> 6, lane = threadIdx.x & 63;
  int idx = blockIdx.x * 4 + wave;            // [0, 16384)
  int tl = idx >> 11, b = idx & 2047;
  int t = t0 + tl;
  const float* pr = part + (size_t)b * 14720 + t * 460;
  const float* br = base + (size_t)b * 460;
  int r0 = lane * 8;
  float vals[8];
  #pragma unroll
  for (int u = 0; u < 8; ++u){
    int r = r0 + u;
    if (r < 460){
      float a = pr[r] * br[r];
      vals[u] = (a == 0.f) ? -1000000000.0f : a;
    } else vals[u] = -__builtin_inff();
  }
  float m = vals[0];
  #pragma unroll
  for (int u = 1; u < 8; ++u) m = fmaxf(m, vals[u]);
  #pragma unroll
  for (int s = 1; s < 64; s <<= 1) m = fmaxf(m, __shfl_xor(m, s));
  float e[8]; float sum = 0.f;
  #pragma unroll
  for (int u = 0; u < 8; ++u){
    float x = vals[u];
    float ev = (x == -__builtin_inff()) ? 0.f : __expf(x - m);
    e[u] = ev; sum += ev;
  }
  #pragma unroll
  for (int s = 1; s < 64; s <<= 1) sum += __shfl_xor(sum, s);
  float inv = 1.f / sum;
  union { u16 o[8]; uint4 v; } pk;
  #pragma unroll
  for (int u = 0; u < 8; ++u) pk.o[u] = f2bf(e[u] * inv);
  *(uint4*)(aout + (size_t)idx * 512 + r0) = pk.v;
}

// ---------------- GRU recurrence: block owns 16 rows, loops t locally -----------------
__global__ __launch_bounds__(256) void gru_scan(
    const u16* __restrict__ gi_all,   // (32*2048, 640) bf16, includes b_ih
    const u16* __restrict__ Whh,      // (640, 256) bf16, zero-padded
    const float* __restrict__ bhh,    // (600)
    const int* __restrict__ cur_ts,   // (2048)
    float* __restrict__ hout)         // (2048, 200)
{
  __shared__ u16 hbf[16 * 256];
  __shared__ float hf[16 * 200];
  __shared__ float ghs[16 * 640];
  __shared__ int mts;
  int tid = threadIdx.x, wave = tid >> 6, lane = tid & 63;
  int rb = blockIdx.x * 16;
  for (int i = tid; i < 16 * 256; i += 256) hbf[i] = 0;
  for (int i = tid; i < 16 * 200; i += 256) hf[i] = 0.f;
  if (tid == 0){
    int m = 0;
    for (int r = 0; r < 16; ++r){ int c = cur_ts[rb + r]; if (c > m) m = c; }
    mts = m;
  }
  __syncthreads();
  int Trun = mts;
  const int fr = lane & 15, fk = (lane >> 4) * 8;
  for (int t = 0; t < Trun; ++t){
    f32x4 acc[10];
    #pragma unroll
    for (int f = 0; f < 10; ++f) acc[f] = (f32x4){0.f, 0.f, 0.f, 0.f};
    #pragma unroll
    for (int ks = 0; ks < 7; ++ks){                    // K = 200 -> 7 x 32
      short8 a = *(const short8*)(hbf + fr * 256 + ks * 32 + fk);
      #pragma unroll
      for (int f = 0; f < 10; ++f){
        int n = wave * 160 + f * 16 + fr;
        short8 b = *(const short8*)(Whh + (size_t)n * 256 + ks * 32 + fk);
        acc[f] = mfma16(a, b, acc[f]);
      }
    }
    #pragma unroll
    for (int f = 0; f < 10; ++f){
      int col = wave * 160 + f * 16 + fr;
      int rbase = (lane >> 4) * 4;
      #pragma unroll
      for (int r = 0; r < 4; ++r) ghs[(rbase + r) * 640 + col] = acc[f][r];
    }
    __syncthreads();
    int d = tid;
    if (d < 200){
      for (int rr = 0; rr < 16; ++rr){
        int gb = rb + rr;
        const u16* gi = gi_all + (size_t)(t * 2048 + gb) * 640;
        float i0 = bf2f(gi[d]), i1 = bf2f(gi[200 + d]), i2 = bf2f(gi[400 + d]);
        float g0 = ghs[rr * 640 + d] + bhh[d];
        float g1 = ghs[rr * 640 + 200 + d] + bhh[200 + d];
        float g2 = ghs[rr * 640 + 400 + d] + bhh[400 + d];
        float r_ = sigf(i0 + g0);
        float z  = sigf(i1 + g1);
        float n_ = tanhf(i2 + r_ * g2);
        float hn = (1.f - z) * n_ + z * hf[rr * 200 + d];
        if (t < cur_ts[gb]){ hf[rr * 200 + d] = hn; hbf[rr * 256 + d] = f2bf(hn); }
      }
    }
    __syncthreads();
  }
  if (tid < 200)
    for (int rr = 0; rr < 16; ++rr)
      hout[(size_t)(rb + rr) * 200 + tid] = hf[rr * 200 + tid];
}

// ---------------- match_loss: mean((ph - h)^2) over 2048x200 -------------------------
__global__ __launch_bounds__(256) void mloss(const float* __restrict__ a,
                                             const float* __restrict__ b,
                                             float* __restrict__ o){
  __shared__ float red[256];
  float s = 0.f;
  for (int i = blockIdx.x * 256 + threadIdx.x; i < 409600; i += gridDim.x * 256){
    float d = a[i] - b[i]; s += d * d;
  }
  red[threadIdx.x] = s; __syncthreads();
  for (int t = 128; t > 0; t >>= 1){
    if (threadIdx.x < t) red[threadIdx.x] += red[threadIdx.x + t];
    __syncthreads();
  }
  if (threadIdx.x == 0) atomicAdd(o, red[0] * (1.f / 409600.f));
}

// ---------------- standalone GRU gate combine (gh = GRU(q_rel, ph)) -------------------
__global__ __launch_bounds__(256) void gru_once(const float* __restrict__ gi,
                                                const float* __restrict__ gg,
                                                const float* __restrict__ hprev,
                                                float* __restrict__ outp){
  int i = blockIdx.x * 256 + threadIdx.x;      // 2048*200
  if (i < 409600){
    int b = i / 200, d = i - b * 200;
    float i0 = gi[b * 600 + d], i1 = gi[b * 600 + 200 + d], i2 = gi[b * 600 + 400 + d];
    float g0 = gg[b * 600 + d], g1 = gg[b * 600 + 200 + d], g2 = gg[b * 600 + 400 + d];
    float r = sigf(i0 + g0);
    float z = sigf(i1 + g1);
    float n = tanhf(i2 + r * g2);
    outp[i] = (1.f - z) * n + z * hprev[i];
  }
}

// ---------------- A_big = (aligned_sub * gh) as bf16, zero-padded ---------------------
__global__ __launch_bounds__(256) void abig_k(const float* __restrict__ al32,
                                              const float* __restrict__ gh2,
                                              const int* __restrict__ trip,
                                              u16* __restrict__ abig){
  int i = blockIdx.x * 256 + threadIdx.x;      // 2048*256
  if (i < 2048 * 256){
    int b = i >> 8, c = i & 255;
    float v = 0.f;
    if (c < 200){
      int sub = trip[b * 3 + 0];
      v = al32[(size_t)sub * 200 + c] * gh2[b * 200 + c];
    }
    abig[i] = f2bf(v);
  }
}

// =====================================================================================
extern "C" void kernel_launch(void* const* d_in, const int* in_sizes, int n_in,
                              void* d_out, int out_size, void* d_ws, size_t ws_size,
                              hipStream_t stream)
{
  (void)in_sizes; (void)n_in; (void)out_size; (void)ws_size;
  const float* pre_emb = (const float*)d_in[0];
  const float* r_emb   = (const float*)d_in[1];
  const int*   trip    = (const int*)d_in[2];
  const float* part    = (const float*)d_in[3];
  const int*   cur_ts  = (const int*)d_in[4];
  const float* Wmap1 = (const float*)d_in[5];   const float* bmap1 = (const float*)d_in[6];
  const float* Wmap2 = (const float*)d_in[7];   const float* bmap2 = (const float*)d_in[8];
  const float* Wattn = (const float*)d_in[9];   const float* battn = (const float*)d_in[10];
  const float* Wih   = (const float*)d_in[11];  const float* Whh   = (const float*)d_in[12];
  const float* bih   = (const float*)d_in[13];  const float* bhh   = (const float*)d_in[14];
  const float* Wh1   = (const float*)d_in[15];  const float* bh1   = (const float*)d_in[16];
  const float* Wh2   = (const float*)d_in[17];  const float* bh2   = (const float*)d_in[18];
  const float* Wal   = (const float*)d_in[19];  const float* bal   = (const float*)d_in[20];
  float* out = (float*)d_out;

  char* wsb = (char*)d_ws;
  size_t off = 0;
  auto alloc = [&](size_t bytes) -> void* {
    void* p = wsb + off;
    off = (off + bytes + 255) & ~(size_t)255;
    return p;
  };
  // bf16 buffers (zero-padded)
  u16* re_bf     = (u16*)alloc((size_t)512 * 256 * 2);
  u16* wmap1_bf  = (u16*)alloc((size_t)512 * 256 * 2);
  u16* wmap2_bf  = (u16*)alloc((size_t)256 * 448 * 2);
  u16* wattn_bf  = (u16*)alloc((size_t)256 * 256 * 2);
  u16* wih_bf    = (u16*)alloc((size_t)640 * 256 * 2);
  u16* whh_bf    = (u16*)alloc((size_t)640 * 256 * 2);
  u16* wh1_bf    = (u16*)alloc((size_t)256 * 256 * 2);
  u16* wh2_bf    = (u16*)alloc((size_t)256 * 256 * 2);
  u16* wal_bf    = (u16*)alloc((size_t)256 * 256 * 2);
  u16* pre_bf    = (u16*)alloc((size_t)10112 * 256 * 2);
  u16* hidden_bf = (u16*)alloc((size_t)512 * 512 * 2);
  u16* mrel_bf   = (u16*)alloc((size_t)512 * 256 * 2);
  u16* mrelT_bf  = (u16*)alloc((size_t)256 * 512 * 2);
  u16* qrel_bf   = (u16*)alloc((size_t)2048 * 256 * 2);
  u16* qa_bf     = (u16*)alloc((size_t)2048 * 256 * 2);
  u16* ph1_bf    = (u16*)alloc((size_t)2048 * 256 * 2);
  u16* ph_bf     = (u16*)alloc((size_t)2048 * 256 * 2);
  u16* abig_bf   = (u16*)alloc((size_t)2048 * 256 * 2);
  u16* a_chunk   = (u16*)alloc((size_t)16384 * 512 * 2);
  u16* x_chunk   = (u16*)alloc((size_t)16384 * 256 * 2);
  u16* gi_all    = (u16*)alloc((size_t)65536 * 640 * 2);
  // fp32 buffers
  float* mrel32 = (float*)alloc((size_t)460 * 200 * 4);
  float* base32 = (float*)alloc((size_t)2048 * 460 * 4);
  float* qrel32 = (float*)alloc((size_t)2048 * 200 * 4);
  float* hout   = (float*)alloc((size_t)2048 * 200 * 4);
  float* ph32   = (float*)alloc((size_t)2048 * 200 * 4);
  float* gi2    = (float*)alloc((size_t)2048 * 600 * 4);
  float* ghg    = (float*)alloc((size_t)2048 * 600 * 4);
  float* gh2    = (float*)alloc((size_t)2048 * 200 * 4);
  float* al32   = (float*)alloc((size_t)10000 * 200 * 4);

  init_out<<<1, 64, 0, stream>>>(out);

  CvtTab tab;
  tab.t[0] = { r_emb,   re_bf,    460, 200,   512, 256 };
  tab.t[1] = { Wmap1,   wmap1_bf, 400, 200,   512, 256 };
  tab.t[2] = { Wmap2,   wmap2_bf, 200, 400,   256, 448 };
  tab.t[3] = { Wattn,   wattn_bf, 200, 200,   256, 256 };
  tab.t[4] = { Wih,     wih_bf,   600, 200,   640, 256 };
  tab.t[5] = { Whh,     whh_bf,   600, 200,   640, 256 };
  tab.t[6] = { Wh1,     wh1_bf,   200, 200,   256, 256 };
  tab.t[7] = { Wh2,     wh2_bf,   200, 200,   256, 256 };
  tab.t[8] = { Wal,     wal_bf,   200, 200,   256, 256 };
  tab.t[9] = { pre_emb, pre_bf, 10000, 200, 10112, 256 };
  cvt_all<<<dim3(512, 10), 256, 0, stream>>>(tab);

  // mapped_rel = (r_emb @ Wmap1^T + b) @ Wmap2^T + b
  gemm_bt<0><<<dim3(4, 4), 256, 0, stream>>>(re_bf, 256, wmap1_bf, 256, 200, 460, 400,
      bmap1, nullptr, hidden_bf, 512, nullptr, nullptr, nullptr);
  gemm_bt<0><<<dim3(2, 4), 256, 0, stream>>>(hidden_bf, 512, wmap2_bf, 448, 400, 460, 200,
      bmap2, mrel32, mrel_bf, 256, nullptr, nullptr, nullptr);
  transpose_mrel<<<512, 256, 0, stream>>>(mrel32, mrelT_bf);
  gather_qrel<<<2048, 256, 0, stream>>>(mrel_bf, mrel32, trip, qrel_bf, qrel32);

  // base = (q_rel @ Wattn^T + b) @ mapped_rel^T
  gemm_bt<0><<<dim3(2, 16), 256, 0, stream>>>(qrel_bf, 256, wattn_bf, 256, 200, 2048, 200,
      battn, nullptr, qa_bf, 256, nullptr, nullptr, nullptr);
  gemm_bt<0><<<dim3(4, 16), 256, 0, stream>>>(qa_bf, 256, mrel_bf, 256, 200, 2048, 460,
      nullptr, base32, nullptr, 0, nullptr, nullptr, nullptr);

  // batched softmax -> x -> gi, 4 chunks of 8 timesteps
  for (int g = 0; g < 4; ++g){
    softmax_k<<<4096, 256, 0, stream>>>(part, base32, g * 8, a_chunk);
    gemm_bt<0><<<dim3(2, 128), 256, 0, stream>>>(a_chunk, 512, mrelT_bf, 512, 460, 16384, 200,
        nullptr, nullptr, x_chunk, 256, nullptr, nullptr, nullptr);
    gemm_bt<0><<<dim3(5, 128), 256, 0, stream>>>(x_chunk, 256, wih_bf, 256, 200, 16384, 600,
        bih, nullptr, gi_all + (size_t)g * 16384 * 640, 640, nullptr, nullptr, nullptr);
  }

  gru_scan<<<128, 256, 0, stream>>>(gi_all, whh_bf, bhh, cur_ts, hout);

  // predicted_hist = 0.1*((q_rel@Wh1^T+b)@Wh2^T+b) + q_rel
  gemm_bt<0><<<dim3(2, 16), 256, 0, stream>>>(qrel_bf, 256, wh1_bf, 256, 200, 2048, 200,
      bh1, nullptr, ph1_bf, 256, nullptr, nullptr, nullptr);
  gemm_bt<1><<<dim3(2, 16), 256, 0, stream>>>(ph1_bf, 256, wh2_bf, 256, 200, 2048, 200,
      bh2, ph32, ph_bf, 256, qrel32, nullptr, nullptr);

  mloss<<<128, 256, 0, stream>>>(ph32, hout, out);

  // gh = GRU(q_rel, predicted_hist)
  gemm_bt<0><<<dim3(5, 16), 256, 0, stream>>>(qrel_bf, 256, wih_bf, 256, 200, 2048, 600,
      bih, gi2, nullptr, 0, nullptr, nullptr, nullptr);
  gemm_bt<0><<<dim3(5, 16), 256, 0, stream>>>(ph_bf, 256, whh_bf, 256, 200, 2048, 600,
      bhh, ghg, nullptr, 0, nullptr, nullptr, nullptr);
  gru_once<<<1600, 256, 0, stream>>>(gi2, ghg, ph32, gh2);

  // aligned_all = pre_emb @ Wal^T + b  (fp32 + bf16)
  gemm_bt<0><<<dim3(2, 79), 256, 0, stream>>>(pre_bf, 256, wal_bf, 256, 200, 10000, 200,
      bal, al32, pre_bf == nullptr ? nullptr : (u16*)nullptr, 0, nullptr, nullptr, nullptr);
  // NOTE: need bf16 aligned for score GEMM; redo with both outputs:
  // (single dispatch writing both — correct call below replaces the line above)
  gemm_bt<0><<<dim3(2, 79), 256, 0, stream>>>(pre_bf, 256, wal_bf, 256, 200, 10000, 200,
      bal, al32, mrelT_bf == nullptr ? nullptr : (u16*)nullptr, 0, nullptr, nullptr, nullptr);
  // The two calls above intentionally only produced fp32; bf16 version:
  {
    static_assert(true, "");
  }
  // Proper aligned bf16 buffer: reuse a_chunk head (16384*512 u16 >= 10112*256)
  u16* al_bf = a_chunk;
  gemm_bt<0><<<dim3(2, 79), 256, 0, stream>>>(pre_bf, 256, wal_bf, 256, 200, 10000, 200,
      bal, al32, al_bf, 256, nullptr, nullptr, nullptr);

  abig_k<<<2048, 256, 0, stream>>>(al32, gh2, trip, abig_bf);

  // score GEMM + fused sigmoid / path_loss epilogue
  gemm_bt<2><<<dim3(79, 16), 256, 0, stream>>>(abig_bf, 256, al_bf, 256, 200, 2048, 10000,
      nullptr, out, nullptr, 0, nullptr, trip, out + 1);
}

// Round 2
// 685.810 us; speedup vs baseline: 1.3018x; 1.3018x over previous
//
#include <hip/hip_runtime.h>
#include <cstdint>
#include <cstddef>

typedef unsigned short u16;
typedef __attribute__((ext_vector_type(8))) short short8;
typedef __attribute__((ext_vector_type(4))) float f32x4;

__device__ __forceinline__ f32x4 mfma16(short8 a, short8 b, f32x4 c){
  return __builtin_amdgcn_mfma_f32_16x16x32_bf16(a, b, c, 0, 0, 0);
}
__device__ __forceinline__ float bf2f(u16 u){
  unsigned v = ((unsigned)u) << 16; float f; __builtin_memcpy(&f, &v, 4); return f;
}
__device__ __forceinline__ u16 f2bf(float f){
  unsigned u; __builtin_memcpy(&u, &f, 4);
  u += 0x7FFFu + ((u >> 16) & 1u);
  return (u16)(u >> 16);
}
__device__ __forceinline__ float sigf(float x){ return 1.f / (1.f + __expf(-x)); }

// ---------------- fp32 -> zero-padded bf16 conversion ----------------
struct CvtD { const float* s; u16* d; int M, K, Mp, Kp; };
struct CvtTab { CvtD t[10]; };

__global__ void cvt_all(CvtTab tab){
  CvtD de = tab.t[blockIdx.y];
  int total = de.Mp * de.Kp;
  for (int i = blockIdx.x * blockDim.x + threadIdx.x; i < total; i += gridDim.x * blockDim.x){
    int r = i / de.Kp, c = i - r * de.Kp;
    float v = (r < de.M && c < de.K) ? de.s[(size_t)r * de.K + c] : 0.f;
    de.d[i] = f2bf(v);
  }
}

__global__ void init_out(float* o){ if (threadIdx.x < 2) o[threadIdx.x] = 0.f; }

// q_rel gather: bf16 row copy + fp32 copy
__global__ void gather_qrel(const u16* __restrict__ mbf, const float* __restrict__ m32,
                            const int* __restrict__ trip, u16* __restrict__ qbf,
                            float* __restrict__ q32){
  int i = blockIdx.x * blockDim.x + threadIdx.x;       // 2048*256
  if (i < 2048 * 256){
    int b = i >> 8, c = i & 255;
    int rel = trip[b * 3 + 1];
    qbf[i] = mbf[rel * 256 + c];
    if (c < 200) q32[b * 200 + c] = m32[rel * 200 + c];
  }
}

// ---------------- generic MFMA GEMM: C = A(M,K) @ B(N,K)^T + bias ----------------
template<int MODE>
__global__ __launch_bounds__(256) void gemm_bt(
    const u16* __restrict__ A, int lda,
    const u16* __restrict__ B, int ldb,
    int K, int Mreal, int Nreal,
    const float* __restrict__ bias,
    float* __restrict__ C32,
    u16* __restrict__ C16, int ldc16,
    const float* __restrict__ extra,
    const int* __restrict__ trip,
    float* __restrict__ loss)
{
  __shared__ u16 As[128 * 64];
  __shared__ u16 Bs[128 * 64];
  __shared__ float red[256];
  const int tid = threadIdx.x;
  const int wave = tid >> 6, lane = tid & 63;
  const int m0 = blockIdx.y * 128, n0 = blockIdx.x * 128;
  const int wm = (wave >> 1) * 64, wn = (wave & 1) * 64;
  const int lr = lane >> 3, lc = (lane & 7) * 8;
  const int fr = lane & 15, fk = (lane >> 4) * 8;

  f32x4 acc[4][4];
  #pragma unroll
  for (int i = 0; i < 4; ++i)
    #pragma unroll
    for (int j = 0; j < 4; ++j) acc[i][j] = (f32x4){0.f, 0.f, 0.f, 0.f};

  const int kT = (K + 63) >> 6;
  for (int kt = 0; kt < kT; ++kt){
    #pragma unroll
    for (int i = 0; i < 4; ++i){
      int ch = wave * 4 + i;
      const u16* ga = A + (size_t)(m0 + ch * 8 + lr) * lda + kt * 64 + lc;
      __builtin_amdgcn_global_load_lds((const __attribute__((address_space(1))) void*)ga,
          (__attribute__((address_space(3))) void*)(As + ch * 512), 16, 0, 0);
      const u16* gb = B + (size_t)(n0 + ch * 8 + lr) * ldb + kt * 64 + lc;
      __builtin_amdgcn_global_load_lds((const __attribute__((address_space(1))) void*)gb,
          (__attribute__((address_space(3))) void*)(Bs + ch * 512), 16, 0, 0);
    }
    __syncthreads();
    #pragma unroll
    for (int ks = 0; ks < 2; ++ks){
      short8 av[4], bv[4];
      #pragma unroll
      for (int i = 0; i < 4; ++i){
        av[i] = *(const short8*)(As + (wm + i * 16 + fr) * 64 + ks * 32 + fk);
        bv[i] = *(const short8*)(Bs + (wn + i * 16 + fr) * 64 + ks * 32 + fk);
      }
      #pragma unroll
      for (int i = 0; i < 4; ++i)
        #pragma unroll
        for (int j = 0; j < 4; ++j)
          acc[i][j] = mfma16(av[i], bv[j], acc[i][j]);
    }
    __syncthreads();
  }

  float lsum = 0.f;
  #pragma unroll
  for (int i = 0; i < 4; ++i){
    #pragma unroll
    for (int j = 0; j < 4; ++j){
      int col = n0 + wn + j * 16 + fr;
      float bvl = 0.f;
      if (bias && col < Nreal) bvl = bias[col];
      #pragma unroll
      for (int r = 0; r < 4; ++r){
        int row = m0 + wm + i * 16 + (lane >> 4) * 4 + r;
        float v = acc[i][j][r] + bvl;
        if (MODE == 0){
          if (C32 && row < Mreal && col < Nreal) C32[(size_t)row * Nreal + col] = v;
          if (C16) C16[(size_t)row * ldc16 + col] =
              (row < Mreal && col < Nreal) ? f2bf(v) : (u16)0;
        } else if (MODE == 1){
          if (row < Mreal){
            if (col < Nreal){
              float pv = 0.1f * v + extra[(size_t)row * Nreal + col];
              C32[(size_t)row * Nreal + col] = pv;
              C16[(size_t)row * ldc16 + col] = f2bf(pv);
            } else {
              C16[(size_t)row * ldc16 + col] = 0;
            }
          }
        } else {
          if (row < Mreal && col < Nreal){
            C32[2 + (size_t)row * Nreal + col] = sigf(v);
            float x = (trip[row * 3 + 2] == col) ? v : -v;
            lsum += fminf(x, 0.f) - log1pf(__expf(-fabsf(x)));
          }
        }
      }
    }
  }
  if (MODE == 2){
    red[tid] = lsum;
    __syncthreads();
    for (int s = 128; s > 0; s >>= 1){
      if (tid < s) red[tid] += red[tid + s];
      __syncthreads();
    }
    if (tid == 0) atomicAdd(loss, -red[0] * (1.f / 20480000.f));
  }
}

// ---------------- masked softmax over R=460, one wave per (t,b) row ----------------
__global__ __launch_bounds__(256) void softmax_k(
    const float* __restrict__ part, const float* __restrict__ base,
    int t0, u16* __restrict__ aout)
{
  int wave = threadIdx.x >> 6, lane = threadIdx.x & 63;
  int idx = blockIdx.x * 4 + wave;            // [0, 16384)
  int tl = idx >> 11, b = idx & 2047;
  int t = t0 + tl;
  const float* pr = part + (size_t)b * 14720 + t * 460;
  const float* br = base + (size_t)b * 460;
  int r0 = lane * 8;
  float vals[8];
  #pragma unroll
  for (int u = 0; u < 8; ++u){
    int r = r0 + u;
    if (r < 460){
      float a = pr[r] * br[r];
      vals[u] = (a == 0.f) ? -1000000000.0f : a;
    } else vals[u] = -__builtin_inff();
  }
  float m = vals[0];
  #pragma unroll
  for (int u = 1; u < 8; ++u) m = fmaxf(m, vals[u]);
  #pragma unroll
  for (int s = 1; s < 64; s <<= 1) m = fmaxf(m, __shfl_xor(m, s));
  float e[8]; float sum = 0.f;
  #pragma unroll
  for (int u = 0; u < 8; ++u){
    float x = vals[u];
    float ev = (x == -__builtin_inff()) ? 0.f : __expf(x - m);
    e[u] = ev; sum += ev;
  }
  #pragma unroll
  for (int s = 1; s < 64; s <<= 1) sum += __shfl_xor(sum, s);
  float inv = 1.f / sum;
  union { u16 o[8]; uint4 v; } pk;
  #pragma unroll
  for (int u = 0; u < 8; ++u) pk.o[u] = f2bf(e[u] * inv);
  *(uint4*)(aout + (size_t)idx * 512 + r0) = pk.v;
}

// ---------------- GRU recurrence v2: 256 blocks x 8 rows, Whh in registers ----------
__global__ __launch_bounds__(256, 1) void gru_scan2(
    const u16* __restrict__ gi_all,   // (65536, 640) bf16, includes b_ih
    const u16* __restrict__ Whh,      // (640, 256) bf16, zero-padded
    const float* __restrict__ bhh,    // (600)
    const int* __restrict__ cur_ts,   // (2048)
    float* __restrict__ hout)         // (2048, 200)
{
  __shared__ u16 hbf[16 * 256];       // swizzled; rows 8..15 stay zero
  __shared__ float hf[8 * 200];
  __shared__ float ghs[8][648];
  __shared__ u16 gis[8 * 640];
  __shared__ float bhs[600];
  __shared__ int cts[8];
  const int tid = threadIdx.x, wave = tid >> 6, lane = tid & 63;
  const int rb = blockIdx.x * 8;
  const int fr = lane & 15, fkg = lane >> 4;
  const int fk = fkg * 8;

  for (int i = tid; i < 16 * 256; i += 256) hbf[i] = 0;
  for (int i = tid; i < 8 * 200; i += 256) hf[i] = 0.f;
  for (int i = tid; i < 600; i += 256) bhs[i] = bhh[i];
  if (tid < 8) cts[tid] = cur_ts[rb + tid];
  __syncthreads();
  int Trun = 0;
  #pragma unroll
  for (int r = 0; r < 8; ++r) Trun = max(Trun, cts[r]);

  // Whh fragments resident in registers for the whole scan (~140 VGPR)
  short8 wb[10][7];
  #pragma unroll
  for (int f = 0; f < 10; ++f)
    #pragma unroll
    for (int ks = 0; ks < 7; ++ks)
      wb[f][ks] = *(const short8*)(Whh + (size_t)(wave * 160 + f * 16 + fr) * 256 + ks * 32 + fk);

  const int grow = tid >> 5;          // gate row 0..7
  const int gl = tid & 31;

  for (int t = 0; t < Trun; ++t){
    // prefetch this step's gi rows (8 contiguous rows = 10240 B) into LDS
    {
      const u16* src = gi_all + ((size_t)t * 2048 + rb) * 640;
      int f = tid;
      #pragma unroll
      for (int j = 0; j < 3; ++j){
        if (f < 640){
          __builtin_amdgcn_global_load_lds(
            (const __attribute__((address_space(1))) void*)(src + f * 8),
            (__attribute__((address_space(3))) void*)(gis + f * 8), 16, 0, 0);
        }
        f += 256;
      }
    }
    // gh = h @ Whh^T : A from swizzled LDS, B from registers
    short8 av[7];
    #pragma unroll
    for (int ks = 0; ks < 7; ++ks)
      av[ks] = *(const short8*)(hbf + ((fr * 256 + ks * 32 + fk) ^ ((fr & 7) << 3)));
    f32x4 acc[10];
    #pragma unroll
    for (int f = 0; f < 10; ++f) acc[f] = (f32x4){0.f, 0.f, 0.f, 0.f};
    #pragma unroll
    for (int ks = 0; ks < 7; ++ks)
      #pragma unroll
      for (int f = 0; f < 10; ++f)
        acc[f] = mfma16(av[ks], wb[f][ks], acc[f]);
    if (fkg < 2){
      #pragma unroll
      for (int f = 0; f < 10; ++f){
        int col = wave * 160 + f * 16 + fr;
        #pragma unroll
        for (int r = 0; r < 4; ++r)
          ghs[fkg * 4 + r][col] = acc[f][r];
      }
    }
    __syncthreads();                  // ghs + gis both ready after this
    const int crow = cts[grow];
    #pragma unroll
    for (int k = 0; k < 7; ++k){
      int d = gl + 32 * k;
      if (d < 200){
        float i0 = bf2f(gis[grow * 640 + d]);
        float i1 = bf2f(gis[grow * 640 + 200 + d]);
        float i2 = bf2f(gis[grow * 640 + 400 + d]);
        float g0 = ghs[grow][d] + bhs[d];
        float g1 = ghs[grow][200 + d] + bhs[200 + d];
        float g2 = ghs[grow][400 + d] + bhs[400 + d];
        float r_ = sigf(i0 + g0);
        float z  = sigf(i1 + g1);
        float xn = i2 + r_ * g2;
        float e2 = __expf(2.f * xn);
        float n_ = 1.f - 2.f / (e2 + 1.f);
        float hn = (1.f - z) * n_ + z * hf[grow * 200 + d];
        if (t < crow){
          hf[grow * 200 + d] = hn;
          hbf[(grow * 256 + d) ^ ((grow & 7) << 3)] = f2bf(hn);
        }
      }
    }
    __syncthreads();
  }
  for (int i = tid; i < 1600; i += 256){
    int row = i / 200, d = i - row * 200;
    hout[(size_t)(rb + row) * 200 + d] = hf[row * 200 + d];
  }
}

// ---------------- match_loss ----------------
__global__ __launch_bounds__(256) void mloss(const float* __restrict__ a,
                                             const float* __restrict__ b,
                                             float* __restrict__ o){
  __shared__ float red[256];
  float s = 0.f;
  for (int i = blockIdx.x * 256 + threadIdx.x; i < 409600; i += gridDim.x * 256){
    float d = a[i] - b[i]; s += d * d;
  }
  red[threadIdx.x] = s; __syncthreads();
  for (int t = 128; t > 0; t >>= 1){
    if (threadIdx.x < t) red[threadIdx.x] += red[threadIdx.x + t];
    __syncthreads();
  }
  if (threadIdx.x == 0) atomicAdd(o, red[0] * (1.f / 409600.f));
}

// ---------------- gh = GRU(q_rel, predicted_hist) gate combine ----------------
__global__ __launch_bounds__(256) void gru_once(const float* __restrict__ gi,
                                                const float* __restrict__ gg,
                                                const float* __restrict__ hprev,
                                                float* __restrict__ outp){
  int i = blockIdx.x * 256 + threadIdx.x;
  if (i < 409600){
    int b = i / 200, d = i - b * 200;
    float i0 = gi[b * 600 + d], i1 = gi[b * 600 + 200 + d], i2 = gi[b * 600 + 400 + d];
    float g0 = gg[b * 600 + d], g1 = gg[b * 600 + 200 + d], g2 = gg[b * 600 + 400 + d];
    float r = sigf(i0 + g0);
    float z = sigf(i1 + g1);
    float n = tanhf(i2 + r * g2);
    outp[i] = (1.f - z) * n + z * hprev[i];
  }
}

// ---------------- A_big = (aligned_sub * gh) as bf16 ----------------
__global__ __launch_bounds__(256) void abig_k(const float* __restrict__ al32,
                                              const float* __restrict__ gh2,
                                              const int* __restrict__ trip,
                                              u16* __restrict__ abig){
  int i = blockIdx.x * 256 + threadIdx.x;
  if (i < 2048 * 256){
    int b = i >> 8, c = i & 255;
    float v = 0.f;
    if (c < 200){
      int sub = trip[b * 3 + 0];
      v = al32[(size_t)sub * 200 + c] * gh2[b * 200 + c];
    }
    abig[i] = f2bf(v);
  }
}

// =====================================================================================
extern "C" void kernel_launch(void* const* d_in, const int* in_sizes, int n_in,
                              void* d_out, int out_size, void* d_ws, size_t ws_size,
                              hipStream_t stream)
{
  (void)in_sizes; (void)n_in; (void)out_size; (void)ws_size;
  const float* pre_emb = (const float*)d_in[0];
  const float* r_emb   = (const float*)d_in[1];
  const int*   trip    = (const int*)d_in[2];
  const float* part    = (const float*)d_in[3];
  const int*   cur_ts  = (const int*)d_in[4];
  const float* Wmap1 = (const float*)d_in[5];   const float* bmap1 = (const float*)d_in[6];
  const float* Wmap2 = (const float*)d_in[7];   const float* bmap2 = (const float*)d_in[8];
  const float* Wattn = (const float*)d_in[9];   const float* battn = (const float*)d_in[10];
  const float* Wih   = (const float*)d_in[11];  const float* Whh   = (const float*)d_in[12];
  const float* bih   = (const float*)d_in[13];  const float* bhh   = (const float*)d_in[14];
  const float* Wh1   = (const float*)d_in[15];  const float* bh1   = (const float*)d_in[16];
  const float* Wh2   = (const float*)d_in[17];  const float* bh2   = (const float*)d_in[18];
  const float* Wal   = (const float*)d_in[19];  const float* bal   = (const float*)d_in[20];
  float* out = (float*)d_out;

  char* wsb = (char*)d_ws;
  size_t off = 0;
  auto alloc = [&](size_t bytes) -> void* {
    void* p = wsb + off;
    off = (off + bytes + 255) & ~(size_t)255;
    return p;
  };
  u16* re_bf     = (u16*)alloc((size_t)512 * 256 * 2);
  u16* wmap1_bf  = (u16*)alloc((size_t)512 * 256 * 2);
  u16* wmap2_bf  = (u16*)alloc((size_t)256 * 448 * 2);
  u16* wattn_bf  = (u16*)alloc((size_t)256 * 256 * 2);
  u16* wih_bf    = (u16*)alloc((size_t)640 * 256 * 2);
  u16* whh_bf    = (u16*)alloc((size_t)640 * 256 * 2);
  u16* wh1_bf    = (u16*)alloc((size_t)256 * 256 * 2);
  u16* wh2_bf    = (u16*)alloc((size_t)256 * 256 * 2);
  u16* wal_bf    = (u16*)alloc((size_t)256 * 256 * 2);
  u16* pre_bf    = (u16*)alloc((size_t)10112 * 256 * 2);
  u16* hidden_bf = (u16*)alloc((size_t)512 * 512 * 2);
  u16* mrel_bf   = (u16*)alloc((size_t)512 * 256 * 2);
  u16* m2t_bf    = (u16*)alloc((size_t)640 * 512 * 2);
  u16* qrel_bf   = (u16*)alloc((size_t)2048 * 256 * 2);
  u16* qa_bf     = (u16*)alloc((size_t)2048 * 256 * 2);
  u16* ph1_bf    = (u16*)alloc((size_t)2048 * 256 * 2);
  u16* ph_bf     = (u16*)alloc((size_t)2048 * 256 * 2);
  u16* abig_bf   = (u16*)alloc((size_t)2048 * 256 * 2);
  u16* a_chunk   = (u16*)alloc((size_t)16384 * 512 * 2);
  u16* gi_all    = (u16*)alloc((size_t)65536 * 640 * 2);
  float* mrel32 = (float*)alloc((size_t)460 * 200 * 4);
  float* base32 = (float*)alloc((size_t)2048 * 460 * 4);
  float* qrel32 = (float*)alloc((size_t)2048 * 200 * 4);
  float* hout   = (float*)alloc((size_t)2048 * 200 * 4);
  float* ph32   = (float*)alloc((size_t)2048 * 200 * 4);
  float* gi2    = (float*)alloc((size_t)2048 * 600 * 4);
  float* ghg    = (float*)alloc((size_t)2048 * 600 * 4);
  float* gh2    = (float*)alloc((size_t)2048 * 200 * 4);
  float* al32   = (float*)alloc((size_t)10000 * 200 * 4);

  init_out<<<1, 64, 0, stream>>>(out);

  CvtTab tab;
  tab.t[0] = { r_emb,   re_bf,    460, 200,   512, 256 };
  tab.t[1] = { Wmap1,   wmap1_bf, 400, 200,   512, 256 };
  tab.t[2] = { Wmap2,   wmap2_bf, 200, 400,   256, 448 };
  tab.t[3] = { Wattn,   wattn_bf, 200, 200,   256, 256 };
  tab.t[4] = { Wih,     wih_bf,   600, 200,   640, 256 };
  tab.t[5] = { Whh,     whh_bf,   600, 200,   640, 256 };
  tab.t[6] = { Wh1,     wh1_bf,   200, 200,   256, 256 };
  tab.t[7] = { Wh2,     wh2_bf,   200, 200,   256, 256 };
  tab.t[8] = { Wal,     wal_bf,   200, 200,   256, 256 };
  tab.t[9] = { pre_emb, pre_bf, 10000, 200, 10112, 256 };
  cvt_all<<<dim3(512, 10), 256, 0, stream>>>(tab);

  // mapped_rel = (r_emb @ Wmap1^T + b) @ Wmap2^T + b
  gemm_bt<0><<<dim3(4, 4), 256, 0, stream>>>(re_bf, 256, wmap1_bf, 256, 200, 460, 400,
      bmap1, nullptr, hidden_bf, 512, nullptr, nullptr, nullptr);
  gemm_bt<0><<<dim3(2, 4), 256, 0, stream>>>(hidden_bf, 512, wmap2_bf, 448, 400, 460, 200,
      bmap2, mrel32, mrel_bf, 256, nullptr, nullptr, nullptr);
  gather_qrel<<<2048, 256, 0, stream>>>(mrel_bf, mrel32, trip, qrel_bf, qrel32);

  // base = (q_rel @ Wattn^T + b) @ mapped_rel^T
  gemm_bt<0><<<dim3(2, 16), 256, 0, stream>>>(qrel_bf, 256, wattn_bf, 256, 200, 2048, 200,
      battn, nullptr, qa_bf, 256, nullptr, nullptr, nullptr);
  gemm_bt<0><<<dim3(4, 16), 256, 0, stream>>>(qa_bf, 256, mrel_bf, 256, 200, 2048, 460,
      nullptr, base32, nullptr, 0, nullptr, nullptr, nullptr);

  // M2T = Wih @ mapped_rel^T  (600 x 460), so gi = a @ M2T^T directly
  gemm_bt<0><<<dim3(4, 5), 256, 0, stream>>>(wih_bf, 256, mrel_bf, 256, 200, 600, 460,
      nullptr, nullptr, m2t_bf, 512, nullptr, nullptr, nullptr);

  // batched softmax -> gi (fused through M2T), 4 chunks of 8 timesteps
  for (int g = 0; g < 4; ++g){
    softmax_k<<<4096, 256, 0, stream>>>(part, base32, g * 8, a_chunk);
    gemm_bt<0><<<dim3(5, 128), 256, 0, stream>>>(a_chunk, 512, m2t_bf, 512, 460, 16384, 600,
        bih, nullptr, gi_all + (size_t)g * 16384 * 640, 640, nullptr, nullptr, nullptr);
  }

  gru_scan2<<<256, 256, 0, stream>>>(gi_all, whh_bf, bhh, cur_ts, hout);

  // predicted_hist = 0.1*((q_rel@Wh1^T+b)@Wh2^T+b) + q_rel
  gemm_bt<0><<<dim3(2, 16), 256, 0, stream>>>(qrel_bf, 256, wh1_bf, 256, 200, 2048, 200,
      bh1, nullptr, ph1_bf, 256, nullptr, nullptr, nullptr);
  gemm_bt<1><<<dim3(2, 16), 256, 0, stream>>>(ph1_bf, 256, wh2_bf, 256, 200, 2048, 200,
      bh2, ph32, ph_bf, 256, qrel32, nullptr, nullptr);

  mloss<<<128, 256, 0, stream>>>(ph32, hout, out);

  // gh = GRU(q_rel, predicted_hist)
  gemm_bt<0><<<dim3(5, 16), 256, 0, stream>>>(qrel_bf, 256, wih_bf, 256, 200, 2048, 600,
      bih, gi2, nullptr, 0, nullptr, nullptr, nullptr);
  gemm_bt<0><<<dim3(5, 16), 256, 0, stream>>>(ph_bf, 256, whh_bf, 256, 200, 2048, 600,
      bhh, ghg, nullptr, 0, nullptr, nullptr, nullptr);
  gru_once<<<1600, 256, 0, stream>>>(gi2, ghg, ph32, gh2);

  // aligned_all = pre_emb @ Wal^T + b  (fp32 + bf16, single dispatch)
  u16* al_bf = a_chunk;               // reuse (chunks fully consumed by now)
  gemm_bt<0><<<dim3(2, 79), 256, 0, stream>>>(pre_bf, 256, wal_bf, 256, 200, 10000, 200,
      bal, al32, al_bf, 256, nullptr, nullptr, nullptr);

  abig_k<<<2048, 256, 0, stream>>>(al32, gh2, trip, abig_bf);

  // score GEMM + fused sigmoid / path_loss epilogue
  gemm_bt<2><<<dim3(79, 16), 256, 0, stream>>>(abig_bf, 256, al_bf, 256, 200, 2048, 10000,
      nullptr, out, nullptr, 0, nullptr, trip, out + 1);
}

// Round 3
// 560.281 us; speedup vs baseline: 1.5934x; 1.2240x over previous
//
#include <hip/hip_runtime.h>
#include <cstdint>
#include <cstddef>

typedef unsigned short u16;
typedef __attribute__((ext_vector_type(8))) short short8;
typedef __attribute__((ext_vector_type(4))) float f32x4;

__device__ __forceinline__ f32x4 mfma16(short8 a, short8 b, f32x4 c){
  return __builtin_amdgcn_mfma_f32_16x16x32_bf16(a, b, c, 0, 0, 0);
}
__device__ __forceinline__ float bf2f(u16 u){
  unsigned v = ((unsigned)u) << 16; float f; __builtin_memcpy(&f, &v, 4); return f;
}
__device__ __forceinline__ u16 f2bf(float f){
  unsigned u; __builtin_memcpy(&u, &f, 4);
  u += 0x7FFFu + ((u >> 16) & 1u);
  return (u16)(u >> 16);
}
__device__ __forceinline__ float sigf(float x){ return 1.f / (1.f + __expf(-x)); }

// ---------------- fp32 -> zero-padded bf16 conversion ----------------
struct CvtD { const float* s; u16* d; int M, K, Mp, Kp; };
struct CvtTab { CvtD t[10]; };

__global__ void cvt_all(CvtTab tab){
  CvtD de = tab.t[blockIdx.y];
  int total = de.Mp * de.Kp;
  for (int i = blockIdx.x * blockDim.x + threadIdx.x; i < total; i += gridDim.x * blockDim.x){
    int r = i / de.Kp, c = i - r * de.Kp;
    float v = (r < de.M && c < de.K) ? de.s[(size_t)r * de.K + c] : 0.f;
    de.d[i] = f2bf(v);
  }
}

__global__ void init_out(float* o){ if (threadIdx.x < 2) o[threadIdx.x] = 0.f; }

// q_rel gather
__global__ void gather_qrel(const u16* __restrict__ mbf, const float* __restrict__ m32,
                            const int* __restrict__ trip, u16* __restrict__ qbf,
                            float* __restrict__ q32){
  int i = blockIdx.x * blockDim.x + threadIdx.x;
  if (i < 2048 * 256){
    int b = i >> 8, c = i & 255;
    int rel = trip[b * 3 + 1];
    qbf[i] = mbf[rel * 256 + c];
    if (c < 200) q32[b * 200 + c] = m32[rel * 200 + c];
  }
}

// ---------------- generic MFMA GEMM: C = A(M,K) @ B(N,K)^T + bias ----------------
// GROUP 0: XCD owns contiguous row-panels (good when B is small / A reused in L2)
// GROUP 1: XCD owns contiguous col-panels (good when B is large: score GEMM)
template<int MODE, int GROUP>
__global__ __launch_bounds__(256) void gemm_bt(
    const u16* __restrict__ A, int lda,
    const u16* __restrict__ B, int ldb,
    int K, int Mreal, int Nreal,
    const float* __restrict__ bias,
    float* __restrict__ C32,
    u16* __restrict__ C16, int ldc16,
    const float* __restrict__ extra,
    const int* __restrict__ trip,
    float* __restrict__ loss)
{
  __shared__ u16 As[128 * 64];
  __shared__ u16 Bs[128 * 64];
  __shared__ float red[256];
  const int tid = threadIdx.x;
  const int wave = tid >> 6, lane = tid & 63;

  // bijective XCD swizzle (m204): round-robin order -> contiguous chunk per XCD
  const int gx = gridDim.x, gy = gridDim.y;
  const int nwg = gx * gy;
  int orig = blockIdx.y * gx + blockIdx.x;
  int q = nwg >> 3, r8 = nwg & 7;
  int xcd = orig & 7, idx = orig >> 3;
  int fid = (xcd < r8 ? xcd * (q + 1) : r8 * (q + 1) + (xcd - r8) * q) + idx;
  int mx, my;
  if (GROUP == 0){ my = fid / gx; mx = fid - my * gx; }
  else           { mx = fid / gy; my = fid - mx * gy; }

  const int m0 = my * 128, n0 = mx * 128;
  const int wm = (wave >> 1) * 64, wn = (wave & 1) * 64;
  const int lr = lane >> 3, lc = (lane & 7) * 8;
  const int fr = lane & 15, fk = (lane >> 4) * 8;

  f32x4 acc[4][4];
  #pragma unroll
  for (int i = 0; i < 4; ++i)
    #pragma unroll
    for (int j = 0; j < 4; ++j) acc[i][j] = (f32x4){0.f, 0.f, 0.f, 0.f};

  const int kT = (K + 63) >> 6;
  for (int kt = 0; kt < kT; ++kt){
    #pragma unroll
    for (int i = 0; i < 4; ++i){
      int ch = wave * 4 + i;
      const u16* ga = A + (size_t)(m0 + ch * 8 + lr) * lda + kt * 64 + lc;
      __builtin_amdgcn_global_load_lds((const __attribute__((address_space(1))) void*)ga,
          (__attribute__((address_space(3))) void*)(As + ch * 512), 16, 0, 0);
      const u16* gb = B + (size_t)(n0 + ch * 8 + lr) * ldb + kt * 64 + lc;
      __builtin_amdgcn_global_load_lds((const __attribute__((address_space(1))) void*)gb,
          (__attribute__((address_space(3))) void*)(Bs + ch * 512), 16, 0, 0);
    }
    __syncthreads();
    #pragma unroll
    for (int ks = 0; ks < 2; ++ks){
      short8 av[4], bv[4];
      #pragma unroll
      for (int i = 0; i < 4; ++i){
        av[i] = *(const short8*)(As + (wm + i * 16 + fr) * 64 + ks * 32 + fk);
        bv[i] = *(const short8*)(Bs + (wn + i * 16 + fr) * 64 + ks * 32 + fk);
      }
      #pragma unroll
      for (int i = 0; i < 4; ++i)
        #pragma unroll
        for (int j = 0; j < 4; ++j)
          acc[i][j] = mfma16(av[i], bv[j], acc[i][j]);
    }
    __syncthreads();
  }

  if (MODE == 2){
    float lsum = 0.f;
    #pragma unroll
    for (int i = 0; i < 4; ++i){
      #pragma unroll
      for (int r = 0; r < 4; ++r){
        int row = m0 + wm + i * 16 + (lane >> 4) * 4 + r;
        int tcol = trip[row * 3 + 2];
        #pragma unroll
        for (int j = 0; j < 4; ++j){
          int col = n0 + wn + j * 16 + fr;
          if (col < Nreal){
            float v = acc[i][j][r];
            float e = __expf(-fabsf(v));
            float inv = __builtin_amdgcn_rcpf(1.f + e);
            C32[2 + (size_t)row * Nreal + col] = (v >= 0.f) ? inv : e * inv;
            float x = (tcol == col) ? v : -v;
            lsum += fminf(x, 0.f) - __logf(1.f + e);
          }
        }
      }
    }
    red[tid] = lsum;
    __syncthreads();
    for (int s = 128; s > 0; s >>= 1){
      if (tid < s) red[tid] += red[tid + s];
      __syncthreads();
    }
    if (tid == 0) atomicAdd(loss, -red[0] * (1.f / 20480000.f));
    return;
  }

  #pragma unroll
  for (int i = 0; i < 4; ++i){
    #pragma unroll
    for (int j = 0; j < 4; ++j){
      int col = n0 + wn + j * 16 + fr;
      float bvl = 0.f;
      if (bias && col < Nreal) bvl = bias[col];
      #pragma unroll
      for (int r = 0; r < 4; ++r){
        int row = m0 + wm + i * 16 + (lane >> 4) * 4 + r;
        float v = acc[i][j][r] + bvl;
        if (MODE == 0){
          if (C32 && row < Mreal && col < Nreal) C32[(size_t)row * Nreal + col] = v;
          if (C16) C16[(size_t)row * ldc16 + col] =
              (row < Mreal && col < Nreal) ? f2bf(v) : (u16)0;
        } else {
          if (row < Mreal){
            if (col < Nreal){
              float pv = 0.1f * v + extra[(size_t)row * Nreal + col];
              C32[(size_t)row * Nreal + col] = pv;
              C16[(size_t)row * ldc16 + col] = f2bf(pv);
            } else {
              C16[(size_t)row * ldc16 + col] = 0;
            }
          }
        }
      }
    }
  }
}

// ---------------- masked softmax over R=460, one wave per (t,b) row ----------------
__global__ __launch_bounds__(256) void softmax_k(
    const float* __restrict__ part, const float* __restrict__ base,
    int t0, u16* __restrict__ aout)
{
  int wave = threadIdx.x >> 6, lane = threadIdx.x & 63;
  int idx = blockIdx.x * 4 + wave;
  int tl = idx >> 11, b = idx & 2047;
  int t = t0 + tl;
  const float* pr = part + (size_t)b * 14720 + t * 460;
  const float* br = base + (size_t)b * 460;
  int r0 = lane * 8;
  float vals[8];
  if (lane < 57){
    float4 pa = *(const float4*)(pr + r0);
    float4 pb = *(const float4*)(pr + r0 + 4);
    float4 ba = *(const float4*)(br + r0);
    float4 bb = *(const float4*)(br + r0 + 4);
    float pv[8] = {pa.x, pa.y, pa.z, pa.w, pb.x, pb.y, pb.z, pb.w};
    float bw[8] = {ba.x, ba.y, ba.z, ba.w, bb.x, bb.y, bb.z, bb.w};
    #pragma unroll
    for (int u = 0; u < 8; ++u){
      float a = pv[u] * bw[u];
      bool valid = (r0 + u) < 460;
      vals[u] = (!valid) ? -__builtin_inff() : ((a == 0.f) ? -1000000000.0f : a);
    }
  } else {
    #pragma unroll
    for (int u = 0; u < 8; ++u){
      int r = r0 + u;
      if (r < 460){
        float a = pr[r] * br[r];
        vals[u] = (a == 0.f) ? -1000000000.0f : a;
      } else vals[u] = -__builtin_inff();
    }
  }
  float m = vals[0];
  #pragma unroll
  for (int u = 1; u < 8; ++u) m = fmaxf(m, vals[u]);
  #pragma unroll
  for (int s = 1; s < 64; s <<= 1) m = fmaxf(m, __shfl_xor(m, s));
  float e[8]; float sum = 0.f;
  #pragma unroll
  for (int u = 0; u < 8; ++u){
    float x = vals[u];
    float ev = (x == -__builtin_inff()) ? 0.f : __expf(x - m);
    e[u] = ev; sum += ev;
  }
  #pragma unroll
  for (int s = 1; s < 64; s <<= 1) sum += __shfl_xor(sum, s);
  float inv = __builtin_amdgcn_rcpf(sum);
  union { u16 o[8]; uint4 v; } pk;
  #pragma unroll
  for (int u = 0; u < 8; ++u) pk.o[u] = f2bf(e[u] * inv);
  *(uint4*)(aout + (size_t)idx * 512 + r0) = pk.v;
}

// ---------------- GRU recurrence: 256 blocks x 8 rows, Whh in registers ----------
__global__ __launch_bounds__(256, 1) void gru_scan2(
    const u16* __restrict__ gi_all,
    const u16* __restrict__ Whh,
    const float* __restrict__ bhh,
    const int* __restrict__ cur_ts,
    float* __restrict__ hout)
{
  __shared__ u16 hbf[16 * 256];
  __shared__ float hf[8 * 200];
  __shared__ float ghs[8][648];
  __shared__ u16 gis[8 * 640];
  __shared__ float bhs[600];
  __shared__ int cts[8];
  const int tid = threadIdx.x, wave = tid >> 6, lane = tid & 63;
  const int rb = blockIdx.x * 8;
  const int fr = lane & 15, fkg = lane >> 4;
  const int fk = fkg * 8;

  for (int i = tid; i < 16 * 256; i += 256) hbf[i] = 0;
  for (int i = tid; i < 8 * 200; i += 256) hf[i] = 0.f;
  for (int i = tid; i < 600; i += 256) bhs[i] = bhh[i];
  if (tid < 8) cts[tid] = cur_ts[rb + tid];
  __syncthreads();
  int Trun = 0;
  #pragma unroll
  for (int r = 0; r < 8; ++r) Trun = max(Trun, cts[r]);

  short8 wb[10][7];
  #pragma unroll
  for (int f = 0; f < 10; ++f)
    #pragma unroll
    for (int ks = 0; ks < 7; ++ks)
      wb[f][ks] = *(const short8*)(Whh + (size_t)(wave * 160 + f * 16 + fr) * 256 + ks * 32 + fk);

  const int grow = tid >> 5;
  const int gl = tid & 31;

  for (int t = 0; t < Trun; ++t){
    {
      const u16* src = gi_all + ((size_t)t * 2048 + rb) * 640;
      int f = tid;
      #pragma unroll
      for (int j = 0; j < 3; ++j){
        if (f < 640){
          __builtin_amdgcn_global_load_lds(
            (const __attribute__((address_space(1))) void*)(src + f * 8),
            (__attribute__((address_space(3))) void*)(gis + f * 8), 16, 0, 0);
        }
        f += 256;
      }
    }
    short8 av[7];
    #pragma unroll
    for (int ks = 0; ks < 7; ++ks)
      av[ks] = *(const short8*)(hbf + ((fr * 256 + ks * 32 + fk) ^ ((fr & 7) << 3)));
    f32x4 acc[10];
    #pragma unroll
    for (int f = 0; f < 10; ++f) acc[f] = (f32x4){0.f, 0.f, 0.f, 0.f};
    #pragma unroll
    for (int ks = 0; ks < 7; ++ks)
      #pragma unroll
      for (int f = 0; f < 10; ++f)
        acc[f] = mfma16(av[ks], wb[f][ks], acc[f]);
    if (fkg < 2){
      #pragma unroll
      for (int f = 0; f < 10; ++f){
        int col = wave * 160 + f * 16 + fr;
        #pragma unroll
        for (int r = 0; r < 4; ++r)
          ghs[fkg * 4 + r][col] = acc[f][r];
      }
    }
    __syncthreads();
    const int crow = cts[grow];
    #pragma unroll
    for (int k = 0; k < 7; ++k){
      int d = gl + 32 * k;
      if (d < 200){
        float i0 = bf2f(gis[grow * 640 + d]);
        float i1 = bf2f(gis[grow * 640 + 200 + d]);
        float i2 = bf2f(gis[grow * 640 + 400 + d]);
        float g0 = ghs[grow][d] + bhs[d];
        float g1 = ghs[grow][200 + d] + bhs[200 + d];
        float g2 = ghs[grow][400 + d] + bhs[400 + d];
        float r_ = sigf(i0 + g0);
        float z  = sigf(i1 + g1);
        float xn = i2 + r_ * g2;
        float e2 = __expf(2.f * xn);
        float n_ = 1.f - 2.f / (e2 + 1.f);
        float hn = (1.f - z) * n_ + z * hf[grow * 200 + d];
        if (t < crow){
          hf[grow * 200 + d] = hn;
          hbf[(grow * 256 + d) ^ ((grow & 7) << 3)] = f2bf(hn);
        }
      }
    }
    __syncthreads();
  }
  for (int i = tid; i < 1600; i += 256){
    int row = i / 200, d = i - row * 200;
    hout[(size_t)(rb + row) * 200 + d] = hf[row * 200 + d];
  }
}

// ---------------- match_loss ----------------
__global__ __launch_bounds__(256) void mloss(const float* __restrict__ a,
                                             const float* __restrict__ b,
                                             float* __restrict__ o){
  __shared__ float red[256];
  float s = 0.f;
  for (int i = blockIdx.x * 256 + threadIdx.x; i < 409600; i += gridDim.x * 256){
    float d = a[i] - b[i]; s += d * d;
  }
  red[threadIdx.x] = s; __syncthreads();
  for (int t = 128; t > 0; t >>= 1){
    if (threadIdx.x < t) red[threadIdx.x] += red[threadIdx.x + t];
    __syncthreads();
  }
  if (threadIdx.x == 0) atomicAdd(o, red[0] * (1.f / 409600.f));
}

// ---------------- gh = GRU(q_rel, predicted_hist) gate combine ----------------
__global__ __launch_bounds__(256) void gru_once(const float* __restrict__ gi,
                                                const float* __restrict__ gg,
                                                const float* __restrict__ hprev,
                                                float* __restrict__ outp){
  int i = blockIdx.x * 256 + threadIdx.x;
  if (i < 409600){
    int b = i / 200, d = i - b * 200;
    float i0 = gi[b * 600 + d], i1 = gi[b * 600 + 200 + d], i2 = gi[b * 600 + 400 + d];
    float g0 = gg[b * 600 + d], g1 = gg[b * 600 + 200 + d], g2 = gg[b * 600 + 400 + d];
    float r = sigf(i0 + g0);
    float z = sigf(i1 + g1);
    float n = tanhf(i2 + r * g2);
    outp[i] = (1.f - z) * n + z * hprev[i];
  }
}

// ---------------- A_big = (aligned_sub * gh) as bf16 ----------------
__global__ __launch_bounds__(256) void abig_k(const float* __restrict__ al32,
                                              const float* __restrict__ gh2,
                                              const int* __restrict__ trip,
                                              u16* __restrict__ abig){
  int i = blockIdx.x * 256 + threadIdx.x;
  if (i < 2048 * 256){
    int b = i >> 8, c = i & 255;
    float v = 0.f;
    if (c < 200){
      int sub = trip[b * 3 + 0];
      v = al32[(size_t)sub * 200 + c] * gh2[b * 200 + c];
    }
    abig[i] = f2bf(v);
  }
}

// =====================================================================================
extern "C" void kernel_launch(void* const* d_in, const int* in_sizes, int n_in,
                              void* d_out, int out_size, void* d_ws, size_t ws_size,
                              hipStream_t stream)
{
  (void)in_sizes; (void)n_in; (void)out_size; (void)ws_size;
  const float* pre_emb = (const float*)d_in[0];
  const float* r_emb   = (const float*)d_in[1];
  const int*   trip    = (const int*)d_in[2];
  const float* part    = (const float*)d_in[3];
  const int*   cur_ts  = (const int*)d_in[4];
  const float* Wmap1 = (const float*)d_in[5];   const float* bmap1 = (const float*)d_in[6];
  const float* Wmap2 = (const float*)d_in[7];   const float* bmap2 = (const float*)d_in[8];
  const float* Wattn = (const float*)d_in[9];   const float* battn = (const float*)d_in[10];
  const float* Wih   = (const float*)d_in[11];  const float* Whh   = (const float*)d_in[12];
  const float* bih   = (const float*)d_in[13];  const float* bhh   = (const float*)d_in[14];
  const float* Wh1   = (const float*)d_in[15];  const float* bh1   = (const float*)d_in[16];
  const float* Wh2   = (const float*)d_in[17];  const float* bh2   = (const float*)d_in[18];
  const float* Wal   = (const float*)d_in[19];  const float* bal   = (const float*)d_in[20];
  float* out = (float*)d_out;

  char* wsb = (char*)d_ws;
  size_t off = 0;
  auto alloc = [&](size_t bytes) -> void* {
    void* p = wsb + off;
    off = (off + bytes + 255) & ~(size_t)255;
    return p;
  };
  u16* re_bf     = (u16*)alloc((size_t)512 * 256 * 2);
  u16* wmap1_bf  = (u16*)alloc((size_t)512 * 256 * 2);
  u16* wmap2_bf  = (u16*)alloc((size_t)256 * 448 * 2);
  u16* wattn_bf  = (u16*)alloc((size_t)256 * 256 * 2);
  u16* wih_bf    = (u16*)alloc((size_t)640 * 256 * 2);
  u16* whh_bf    = (u16*)alloc((size_t)640 * 256 * 2);
  u16* wh1_bf    = (u16*)alloc((size_t)256 * 256 * 2);
  u16* wh2_bf    = (u16*)alloc((size_t)256 * 256 * 2);
  u16* wal_bf    = (u16*)alloc((size_t)256 * 256 * 2);
  u16* pre_bf    = (u16*)alloc((size_t)10112 * 256 * 2);
  u16* hidden_bf = (u16*)alloc((size_t)512 * 512 * 2);
  u16* mrel_bf   = (u16*)alloc((size_t)512 * 256 * 2);
  u16* m2t_bf    = (u16*)alloc((size_t)640 * 512 * 2);
  u16* qrel_bf   = (u16*)alloc((size_t)2048 * 256 * 2);
  u16* qa_bf     = (u16*)alloc((size_t)2048 * 256 * 2);
  u16* ph1_bf    = (u16*)alloc((size_t)2048 * 256 * 2);
  u16* ph_bf     = (u16*)alloc((size_t)2048 * 256 * 2);
  u16* abig_bf   = (u16*)alloc((size_t)2048 * 256 * 2);
  u16* a_chunk   = (u16*)alloc((size_t)16384 * 512 * 2);
  u16* gi_all    = (u16*)alloc((size_t)65536 * 640 * 2);
  float* mrel32 = (float*)alloc((size_t)460 * 200 * 4);
  float* base32 = (float*)alloc((size_t)2048 * 460 * 4);
  float* qrel32 = (float*)alloc((size_t)2048 * 200 * 4);
  float* hout   = (float*)alloc((size_t)2048 * 200 * 4);
  float* ph32   = (float*)alloc((size_t)2048 * 200 * 4);
  float* gi2    = (float*)alloc((size_t)2048 * 600 * 4);
  float* ghg    = (float*)alloc((size_t)2048 * 600 * 4);
  float* gh2    = (float*)alloc((size_t)2048 * 200 * 4);
  float* al32   = (float*)alloc((size_t)10000 * 200 * 4);

  init_out<<<1, 64, 0, stream>>>(out);

  CvtTab tab;
  tab.t[0] = { r_emb,   re_bf,    460, 200,   512, 256 };
  tab.t[1] = { Wmap1,   wmap1_bf, 400, 200,   512, 256 };
  tab.t[2] = { Wmap2,   wmap2_bf, 200, 400,   256, 448 };
  tab.t[3] = { Wattn,   wattn_bf, 200, 200,   256, 256 };
  tab.t[4] = { Wih,     wih_bf,   600, 200,   640, 256 };
  tab.t[5] = { Whh,     whh_bf,   600, 200,   640, 256 };
  tab.t[6] = { Wh1,     wh1_bf,   200, 200,   256, 256 };
  tab.t[7] = { Wh2,     wh2_bf,   200, 200,   256, 256 };
  tab.t[8] = { Wal,     wal_bf,   200, 200,   256, 256 };
  tab.t[9] = { pre_emb, pre_bf, 10000, 200, 10112, 256 };
  cvt_all<<<dim3(512, 10), 256, 0, stream>>>(tab);

  gemm_bt<0,0><<<dim3(4, 4), 256, 0, stream>>>(re_bf, 256, wmap1_bf, 256, 200, 460, 400,
      bmap1, nullptr, hidden_bf, 512, nullptr, nullptr, nullptr);
  gemm_bt<0,0><<<dim3(2, 4), 256, 0, stream>>>(hidden_bf, 512, wmap2_bf, 448, 400, 460, 200,
      bmap2, mrel32, mrel_bf, 256, nullptr, nullptr, nullptr);
  gather_qrel<<<2048, 256, 0, stream>>>(mrel_bf, mrel32, trip, qrel_bf, qrel32);

  gemm_bt<0,0><<<dim3(2, 16), 256, 0, stream>>>(qrel_bf, 256, wattn_bf, 256, 200, 2048, 200,
      battn, nullptr, qa_bf, 256, nullptr, nullptr, nullptr);
  gemm_bt<0,0><<<dim3(4, 16), 256, 0, stream>>>(qa_bf, 256, mrel_bf, 256, 200, 2048, 460,
      nullptr, base32, nullptr, 0, nullptr, nullptr, nullptr);

  // M2T = Wih @ mapped_rel^T  (600 x 460)
  gemm_bt<0,0><<<dim3(4, 5), 256, 0, stream>>>(wih_bf, 256, mrel_bf, 256, 200, 600, 460,
      nullptr, nullptr, m2t_bf, 512, nullptr, nullptr, nullptr);

  for (int g = 0; g < 4; ++g){
    softmax_k<<<4096, 256, 0, stream>>>(part, base32, g * 8, a_chunk);
    gemm_bt<0,0><<<dim3(5, 128), 256, 0, stream>>>(a_chunk, 512, m2t_bf, 512, 460, 16384, 600,
        bih, nullptr, gi_all + (size_t)g * 16384 * 640, 640, nullptr, nullptr, nullptr);
  }

  gru_scan2<<<256, 256, 0, stream>>>(gi_all, whh_bf, bhh, cur_ts, hout);

  gemm_bt<0,0><<<dim3(2, 16), 256, 0, stream>>>(qrel_bf, 256, wh1_bf, 256, 200, 2048, 200,
      bh1, nullptr, ph1_bf, 256, nullptr, nullptr, nullptr);
  gemm_bt<1,0><<<dim3(2, 16), 256, 0, stream>>>(ph1_bf, 256, wh2_bf, 256, 200, 2048, 200,
      bh2, ph32, ph_bf, 256, qrel32, nullptr, nullptr);

  mloss<<<128, 256, 0, stream>>>(ph32, hout, out);

  gemm_bt<0,0><<<dim3(5, 16), 256, 0, stream>>>(qrel_bf, 256, wih_bf, 256, 200, 2048, 600,
      bih, gi2, nullptr, 0, nullptr, nullptr, nullptr);
  gemm_bt<0,0><<<dim3(5, 16), 256, 0, stream>>>(ph_bf, 256, whh_bf, 256, 200, 2048, 600,
      bhh, ghg, nullptr, 0, nullptr, nullptr, nullptr);
  gru_once<<<1600, 256, 0, stream>>>(gi2, ghg, ph32, gh2);

  u16* al_bf = a_chunk;
  gemm_bt<0,0><<<dim3(2, 79), 256, 0, stream>>>(pre_bf, 256, wal_bf, 256, 200, 10000, 200,
      bal, al32, al_bf, 256, nullptr, nullptr, nullptr);

  abig_k<<<2048, 256, 0, stream>>>(al32, gh2, trip, abig_bf);

  gemm_bt<2,1><<<dim3(79, 16), 256, 0, stream>>>(abig_bf, 256, al_bf, 256, 200, 2048, 10000,
      nullptr, out, nullptr, 0, nullptr, trip, out + 1);
}

// Round 4
// 513.451 us; speedup vs baseline: 1.7388x; 1.0912x over previous
//
#include <hip/hip_runtime.h>
#include <cstdint>
#include <cstddef>

typedef unsigned short u16;
typedef __attribute__((ext_vector_type(8))) short short8;
typedef __attribute__((ext_vector_type(4))) float f32x4;

__device__ __forceinline__ f32x4 mfma16(short8 a, short8 b, f32x4 c){
  return __builtin_amdgcn_mfma_f32_16x16x32_bf16(a, b, c, 0, 0, 0);
}
__device__ __forceinline__ float bf2f(u16 u){
  unsigned v = ((unsigned)u) << 16; float f; __builtin_memcpy(&f, &v, 4); return f;
}
__device__ __forceinline__ u16 f2bf(float f){
  unsigned u; __builtin_memcpy(&u, &f, 4);
  u += 0x7FFFu + ((u >> 16) & 1u);
  return (u16)(u >> 16);
}
__device__ __forceinline__ float sigf(float x){ return 1.f / (1.f + __expf(-x)); }

// ---------------- fp32 -> zero-padded bf16 conversion ----------------
struct CvtD { const float* s; u16* d; int M, K, Mp, Kp; };
struct CvtTab { CvtD t[10]; };

__global__ void cvt_all(CvtTab tab){
  CvtD de = tab.t[blockIdx.y];
  int total = de.Mp * de.Kp;
  for (int i = blockIdx.x * blockDim.x + threadIdx.x; i < total; i += gridDim.x * blockDim.x){
    int r = i / de.Kp, c = i - r * de.Kp;
    float v = (r < de.M && c < de.K) ? de.s[(size_t)r * de.K + c] : 0.f;
    de.d[i] = f2bf(v);
  }
}

__global__ void init_out(float* o){ if (threadIdx.x < 2) o[threadIdx.x] = 0.f; }

// q_rel gather
__global__ void gather_qrel(const u16* __restrict__ mbf, const float* __restrict__ m32,
                            const int* __restrict__ trip, u16* __restrict__ qbf,
                            float* __restrict__ q32){
  int i = blockIdx.x * blockDim.x + threadIdx.x;
  if (i < 2048 * 256){
    int b = i >> 8, c = i & 255;
    int rel = trip[b * 3 + 1];
    qbf[i] = mbf[rel * 256 + c];
    if (c < 200) q32[b * 200 + c] = m32[rel * 200 + c];
  }
}

// ---------------- generic MFMA GEMM: C = A(M,K) @ B(N,K)^T + bias ----------------
template<int MODE, int GROUP>
__global__ __launch_bounds__(256) void gemm_bt(
    const u16* __restrict__ A, int lda,
    const u16* __restrict__ B, int ldb,
    int K, int Mreal, int Nreal,
    const float* __restrict__ bias,
    float* __restrict__ C32,
    u16* __restrict__ C16, int ldc16,
    const float* __restrict__ extra,
    const int* __restrict__ trip,
    float* __restrict__ loss)
{
  __shared__ u16 As[128 * 64];
  __shared__ u16 Bs[128 * 64];
  __shared__ float red[256];
  const int tid = threadIdx.x;
  const int wave = tid >> 6, lane = tid & 63;

  const int gx = gridDim.x, gy = gridDim.y;
  const int nwg = gx * gy;
  int orig = blockIdx.y * gx + blockIdx.x;
  int q = nwg >> 3, r8 = nwg & 7;
  int xcd = orig & 7, idx = orig >> 3;
  int fid = (xcd < r8 ? xcd * (q + 1) : r8 * (q + 1) + (xcd - r8) * q) + idx;
  int mx, my;
  if (GROUP == 0){ my = fid / gx; mx = fid - my * gx; }
  else           { mx = fid / gy; my = fid - mx * gy; }

  const int m0 = my * 128, n0 = mx * 128;
  const int wm = (wave >> 1) * 64, wn = (wave & 1) * 64;
  const int lr = lane >> 3, lc = (lane & 7) * 8;
  const int fr = lane & 15, fk = (lane >> 4) * 8;

  f32x4 acc[4][4];
  #pragma unroll
  for (int i = 0; i < 4; ++i)
    #pragma unroll
    for (int j = 0; j < 4; ++j) acc[i][j] = (f32x4){0.f, 0.f, 0.f, 0.f};

  const int kT = (K + 63) >> 6;
  for (int kt = 0; kt < kT; ++kt){
    #pragma unroll
    for (int i = 0; i < 4; ++i){
      int ch = wave * 4 + i;
      const u16* ga = A + (size_t)(m0 + ch * 8 + lr) * lda + kt * 64 + lc;
      __builtin_amdgcn_global_load_lds((const __attribute__((address_space(1))) void*)ga,
          (__attribute__((address_space(3))) void*)(As + ch * 512), 16, 0, 0);
      const u16* gb = B + (size_t)(n0 + ch * 8 + lr) * ldb + kt * 64 + lc;
      __builtin_amdgcn_global_load_lds((const __attribute__((address_space(1))) void*)gb,
          (__attribute__((address_space(3))) void*)(Bs + ch * 512), 16, 0, 0);
    }
    __syncthreads();
    #pragma unroll
    for (int ks = 0; ks < 2; ++ks){
      short8 av[4], bv[4];
      #pragma unroll
      for (int i = 0; i < 4; ++i){
        av[i] = *(const short8*)(As + (wm + i * 16 + fr) * 64 + ks * 32 + fk);
        bv[i] = *(const short8*)(Bs + (wn + i * 16 + fr) * 64 + ks * 32 + fk);
      }
      #pragma unroll
      for (int i = 0; i < 4; ++i)
        #pragma unroll
        for (int j = 0; j < 4; ++j)
          acc[i][j] = mfma16(av[i], bv[j], acc[i][j]);
    }
    __syncthreads();
  }

  if (MODE == 2){
    float lsum = 0.f;
    #pragma unroll
    for (int i = 0; i < 4; ++i){
      #pragma unroll
      for (int r = 0; r < 4; ++r){
        int row = m0 + wm + i * 16 + (lane >> 4) * 4 + r;
        int tcol = trip[row * 3 + 2];
        #pragma unroll
        for (int j = 0; j < 4; ++j){
          int col = n0 + wn + j * 16 + fr;
          if (col < Nreal){
            float v = acc[i][j][r];
            float e = __expf(-fabsf(v));
            float inv = __builtin_amdgcn_rcpf(1.f + e);
            C32[2 + (size_t)row * Nreal + col] = (v >= 0.f) ? inv : e * inv;
            float x = (tcol == col) ? v : -v;
            lsum += fminf(x, 0.f) - __logf(1.f + e);
          }
        }
      }
    }
    red[tid] = lsum;
    __syncthreads();
    for (int s = 128; s > 0; s >>= 1){
      if (tid < s) red[tid] += red[tid + s];
      __syncthreads();
    }
    if (tid == 0) atomicAdd(loss, -red[0] * (1.f / 20480000.f));
    return;
  }

  #pragma unroll
  for (int i = 0; i < 4; ++i){
    #pragma unroll
    for (int j = 0; j < 4; ++j){
      int col = n0 + wn + j * 16 + fr;
      float bvl = 0.f;
      if (bias && col < Nreal) bvl = bias[col];
      #pragma unroll
      for (int r = 0; r < 4; ++r){
        int row = m0 + wm + i * 16 + (lane >> 4) * 4 + r;
        float v = acc[i][j][r] + bvl;
        if (MODE == 0){
          if (C32 && row < Mreal && col < Nreal) C32[(size_t)row * Nreal + col] = v;
          if (C16) C16[(size_t)row * ldc16 + col] =
              (row < Mreal && col < Nreal) ? f2bf(v) : (u16)0;
        } else {
          if (row < Mreal){
            if (col < Nreal){
              float pv = 0.1f * v + extra[(size_t)row * Nreal + col];
              C32[(size_t)row * Nreal + col] = pv;
              C16[(size_t)row * ldc16 + col] = f2bf(pv);
            } else {
              C16[(size_t)row * ldc16 + col] = 0;
            }
          }
        }
      }
    }
  }
}

// ---------------- masked softmax over R=460 ----------------
__global__ __launch_bounds__(256) void softmax_k(
    const float* __restrict__ part, const float* __restrict__ base,
    int t0, u16* __restrict__ aout)
{
  int wave = threadIdx.x >> 6, lane = threadIdx.x & 63;
  int idx = blockIdx.x * 4 + wave;
  int tl = idx >> 11, b = idx & 2047;
  int t = t0 + tl;
  const float* pr = part + (size_t)b * 14720 + t * 460;
  const float* br = base + (size_t)b * 460;
  int r0 = lane * 8;
  float vals[8];
  if (lane < 57){
    float4 pa = *(const float4*)(pr + r0);
    float4 pb = *(const float4*)(pr + r0 + 4);
    float4 ba = *(const float4*)(br + r0);
    float4 bb = *(const float4*)(br + r0 + 4);
    float pv[8] = {pa.x, pa.y, pa.z, pa.w, pb.x, pb.y, pb.z, pb.w};
    float bw[8] = {ba.x, ba.y, ba.z, ba.w, bb.x, bb.y, bb.z, bb.w};
    #pragma unroll
    for (int u = 0; u < 8; ++u){
      float a = pv[u] * bw[u];
      bool valid = (r0 + u) < 460;
      vals[u] = (!valid) ? -__builtin_inff() : ((a == 0.f) ? -1000000000.0f : a);
    }
  } else {
    #pragma unroll
    for (int u = 0; u < 8; ++u){
      int r = r0 + u;
      if (r < 460){
        float a = pr[r] * br[r];
        vals[u] = (a == 0.f) ? -1000000000.0f : a;
      } else vals[u] = -__builtin_inff();
    }
  }
  float m = vals[0];
  #pragma unroll
  for (int u = 1; u < 8; ++u) m = fmaxf(m, vals[u]);
  #pragma unroll
  for (int s = 1; s < 64; s <<= 1) m = fmaxf(m, __shfl_xor(m, s));
  float e[8]; float sum = 0.f;
  #pragma unroll
  for (int u = 0; u < 8; ++u){
    float x = vals[u];
    float ev = (x == -__builtin_inff()) ? 0.f : __expf(x - m);
    e[u] = ev; sum += ev;
  }
  #pragma unroll
  for (int s = 1; s < 64; s <<= 1) sum += __shfl_xor(sum, s);
  float inv = __builtin_amdgcn_rcpf(sum);
  union { u16 o[8]; uint4 v; } pk;
  #pragma unroll
  for (int u = 0; u < 8; ++u) pk.o[u] = f2bf(e[u] * inv);
  *(uint4*)(aout + (size_t)idx * 512 + r0) = pk.v;
}

// ---------------- GRU recurrence v3: 256 blocks x 8 rows x 8 waves ------------------
// wave w owns Whh cols [80w, 80w+80) in registers; gate phase: one wave per row.
// gi double-buffered via global_load_lds kept in flight across raw s_barriers.
__global__ __launch_bounds__(512, 2) void gru_scan3(
    const u16* __restrict__ gi_all,   // (65536, 640) bf16 incl. b_ih
    const u16* __restrict__ Whh,      // (640, 256) bf16 zero-padded
    const float* __restrict__ bhh,    // (600)
    const int* __restrict__ cur_ts,   // (2048)
    float* __restrict__ hout)         // (2048, 200)
{
  __shared__ u16 hbf[16 * 256];       // swizzled; rows 8..15 stay zero
  __shared__ float hf[8 * 200];
  __shared__ float ghs[8][648];
  __shared__ u16 gis[2][8 * 640];
  __shared__ float bhs[600];
  __shared__ int cts[8];
  const int tid = threadIdx.x, wave = tid >> 6, lane = tid & 63;
  const int rb = blockIdx.x * 8;
  const int fr = lane & 15, fkg = lane >> 4;
  const int fk = fkg * 8;

  for (int i = tid; i < 16 * 256; i += 512) hbf[i] = 0;
  for (int i = tid; i < 8 * 200; i += 512) hf[i] = 0.f;
  for (int i = tid; i < 600; i += 512) bhs[i] = bhh[i];
  if (tid < 8) cts[tid] = cur_ts[rb + tid];
  __syncthreads();
  int Trun = 0;
  #pragma unroll
  for (int r = 0; r < 8; ++r) Trun = max(Trun, cts[r]);

  // Whh fragments: wave w holds cols [80w, 80w+80): 35 short8 ~ 140 regs
  short8 wb[5][7];
  #pragma unroll
  for (int f = 0; f < 5; ++f)
    #pragma unroll
    for (int ks = 0; ks < 7; ++ks)
      wb[f][ks] = *(const short8*)(Whh + (size_t)(wave * 80 + f * 16 + fr) * 256 + ks * 32 + fk);

  // prologue: prefetch gis[0] for t=0
  if (Trun > 0){
    const u16* src = gi_all + (size_t)rb * 640;
    __builtin_amdgcn_global_load_lds(
        (const __attribute__((address_space(1))) void*)(src + tid * 8),
        (__attribute__((address_space(3))) void*)(&gis[0][0] + tid * 8), 16, 0, 0);
    if (tid < 128)
      __builtin_amdgcn_global_load_lds(
          (const __attribute__((address_space(1))) void*)(src + (512 + tid) * 8),
          (__attribute__((address_space(3))) void*)(&gis[0][0] + (512 + tid) * 8), 16, 0, 0);
  }
  __syncthreads();                      // drains vmcnt: gis[0] + wb ready

  const int grow = wave;                // gate: one wave per row
  const int crow = (Trun > 0) ? cts[grow] : 0;

  for (int t = 0; t < Trun; ++t){
    // ---- phase 1: gh = h @ Whh^T (A from swizzled LDS, B from registers) ----
    f32x4 acc[5];
    #pragma unroll
    for (int f = 0; f < 5; ++f) acc[f] = (f32x4){0.f, 0.f, 0.f, 0.f};
    #pragma unroll
    for (int ks = 0; ks < 7; ++ks){
      short8 av = *(const short8*)(hbf + ((fr * 256 + ks * 32 + fk) ^ ((fr & 7) << 3)));
      #pragma unroll
      for (int f = 0; f < 5; ++f)
        acc[f] = mfma16(av, wb[f][ks], acc[f]);
    }
    if (fkg < 2){
      #pragma unroll
      for (int f = 0; f < 5; ++f){
        int col = wave * 80 + f * 16 + fr;
        #pragma unroll
        for (int r = 0; r < 4; ++r)
          ghs[fkg * 4 + r][col] = acc[f][r];
      }
    }
    // barrier1: ghs visible AND this step's gis buffer landed (vmcnt)
    __builtin_amdgcn_sched_barrier(0);
    asm volatile("s_waitcnt vmcnt(0) lgkmcnt(0)" ::: "memory");
    __builtin_amdgcn_sched_barrier(0);
    __builtin_amdgcn_s_barrier();
    __builtin_amdgcn_sched_barrier(0);

    // issue prefetch for t+1 (stays in flight across barrier2 + next MFMA phase)
    if (t + 1 < Trun){
      const u16* src = gi_all + ((size_t)(t + 1) * 2048 + rb) * 640;
      u16* dst = &gis[(t + 1) & 1][0];
      __builtin_amdgcn_global_load_lds(
          (const __attribute__((address_space(1))) void*)(src + tid * 8),
          (__attribute__((address_space(3))) void*)(dst + tid * 8), 16, 0, 0);
      if (tid < 128)
        __builtin_amdgcn_global_load_lds(
            (const __attribute__((address_space(1))) void*)(src + (512 + tid) * 8),
            (__attribute__((address_space(3))) void*)(dst + (512 + tid) * 8), 16, 0, 0);
    }

    // ---- phase 2: gate combine (wave-uniform row predicate) ----
    if (t < crow){
      const u16* gr = &gis[t & 1][0] + grow * 640;
      #pragma unroll
      for (int k = 0; k < 4; ++k){
        int d = lane + 64 * k;
        if (d < 200){
          float i0 = bf2f(gr[d]);
          float i1 = bf2f(gr[200 + d]);
          float i2 = bf2f(gr[400 + d]);
          float g0 = ghs[grow][d] + bhs[d];
          float g1 = ghs[grow][200 + d] + bhs[200 + d];
          float g2 = ghs[grow][400 + d] + bhs[400 + d];
          float e0 = __expf(-(i0 + g0));
          float r_ = __builtin_amdgcn_rcpf(1.f + e0);
          float e1 = __expf(-(i1 + g1));
          float z  = __builtin_amdgcn_rcpf(1.f + e1);
          float xn = i2 + r_ * g2;
          float e2 = __expf(2.f * xn);
          float n_ = 1.f - 2.f * __builtin_amdgcn_rcpf(e2 + 1.f);
          float hn = (1.f - z) * n_ + z * hf[grow * 200 + d];
          hf[grow * 200 + d] = hn;
          hbf[(grow * 256 + d) ^ (grow << 3)] = f2bf(hn);
        }
      }
    }
    // barrier2: hbf/hf visible; do NOT drain vmcnt (t+1 prefetch in flight)
    __builtin_amdgcn_sched_barrier(0);
    asm volatile("s_waitcnt lgkmcnt(0)" ::: "memory");
    __builtin_amdgcn_sched_barrier(0);
    __builtin_amdgcn_s_barrier();
    __builtin_amdgcn_sched_barrier(0);
  }

  for (int i = tid; i < 1600; i += 512){
    int row = i / 200, d = i - row * 200;
    hout[(size_t)(rb + row) * 200 + d] = hf[row * 200 + d];
  }
}

// ---------------- match_loss ----------------
__global__ __launch_bounds__(256) void mloss(const float* __restrict__ a,
                                             const float* __restrict__ b,
                                             float* __restrict__ o){
  __shared__ float red[256];
  float s = 0.f;
  for (int i = blockIdx.x * 256 + threadIdx.x; i < 409600; i += gridDim.x * 256){
    float d = a[i] - b[i]; s += d * d;
  }
  red[threadIdx.x] = s; __syncthreads();
  for (int t = 128; t > 0; t >>= 1){
    if (threadIdx.x < t) red[threadIdx.x] += red[threadIdx.x + t];
    __syncthreads();
  }
  if (threadIdx.x == 0) atomicAdd(o, red[0] * (1.f / 409600.f));
}

// ---------------- gh = GRU(q_rel, predicted_hist) gate combine ----------------
__global__ __launch_bounds__(256) void gru_once(const float* __restrict__ gi,
                                                const float* __restrict__ gg,
                                                const float* __restrict__ hprev,
                                                float* __restrict__ outp){
  int i = blockIdx.x * 256 + threadIdx.x;
  if (i < 409600){
    int b = i / 200, d = i - b * 200;
    float i0 = gi[b * 600 + d], i1 = gi[b * 600 + 200 + d], i2 = gi[b * 600 + 400 + d];
    float g0 = gg[b * 600 + d], g1 = gg[b * 600 + 200 + d], g2 = gg[b * 600 + 400 + d];
    float r = sigf(i0 + g0);
    float z = sigf(i1 + g1);
    float n = tanhf(i2 + r * g2);
    outp[i] = (1.f - z) * n + z * hprev[i];
  }
}

// ---------------- A_big = (aligned_sub * gh) as bf16 ----------------
__global__ __launch_bounds__(256) void abig_k(const float* __restrict__ al32,
                                              const float* __restrict__ gh2,
                                              const int* __restrict__ trip,
                                              u16* __restrict__ abig){
  int i = blockIdx.x * 256 + threadIdx.x;
  if (i < 2048 * 256){
    int b = i >> 8, c = i & 255;
    float v = 0.f;
    if (c < 200){
      int sub = trip[b * 3 + 0];
      v = al32[(size_t)sub * 200 + c] * gh2[b * 200 + c];
    }
    abig[i] = f2bf(v);
  }
}

// =====================================================================================
extern "C" void kernel_launch(void* const* d_in, const int* in_sizes, int n_in,
                              void* d_out, int out_size, void* d_ws, size_t ws_size,
                              hipStream_t stream)
{
  (void)in_sizes; (void)n_in; (void)out_size; (void)ws_size;
  const float* pre_emb = (const float*)d_in[0];
  const float* r_emb   = (const float*)d_in[1];
  const int*   trip    = (const int*)d_in[2];
  const float* part    = (const float*)d_in[3];
  const int*   cur_ts  = (const int*)d_in[4];
  const float* Wmap1 = (const float*)d_in[5];   const float* bmap1 = (const float*)d_in[6];
  const float* Wmap2 = (const float*)d_in[7];   const float* bmap2 = (const float*)d_in[8];
  const float* Wattn = (const float*)d_in[9];   const float* battn = (const float*)d_in[10];
  const float* Wih   = (const float*)d_in[11];  const float* Whh   = (const float*)d_in[12];
  const float* bih   = (const float*)d_in[13];  const float* bhh   = (const float*)d_in[14];
  const float* Wh1   = (const float*)d_in[15];  const float* bh1   = (const float*)d_in[16];
  const float* Wh2   = (const float*)d_in[17];  const float* bh2   = (const float*)d_in[18];
  const float* Wal   = (const float*)d_in[19];  const float* bal   = (const float*)d_in[20];
  float* out = (float*)d_out;

  char* wsb = (char*)d_ws;
  size_t off = 0;
  auto alloc = [&](size_t bytes) -> void* {
    void* p = wsb + off;
    off = (off + bytes + 255) & ~(size_t)255;
    return p;
  };
  u16* re_bf     = (u16*)alloc((size_t)512 * 256 * 2);
  u16* wmap1_bf  = (u16*)alloc((size_t)512 * 256 * 2);
  u16* wmap2_bf  = (u16*)alloc((size_t)256 * 448 * 2);
  u16* wattn_bf  = (u16*)alloc((size_t)256 * 256 * 2);
  u16* wih_bf    = (u16*)alloc((size_t)640 * 256 * 2);
  u16* whh_bf    = (u16*)alloc((size_t)640 * 256 * 2);
  u16* wh1_bf    = (u16*)alloc((size_t)256 * 256 * 2);
  u16* wh2_bf    = (u16*)alloc((size_t)256 * 256 * 2);
  u16* wal_bf    = (u16*)alloc((size_t)256 * 256 * 2);
  u16* pre_bf    = (u16*)alloc((size_t)10112 * 256 * 2);
  u16* hidden_bf = (u16*)alloc((size_t)512 * 512 * 2);
  u16* mrel_bf   = (u16*)alloc((size_t)512 * 256 * 2);
  u16* m2t_bf    = (u16*)alloc((size_t)640 * 512 * 2);
  u16* qrel_bf   = (u16*)alloc((size_t)2048 * 256 * 2);
  u16* qa_bf     = (u16*)alloc((size_t)2048 * 256 * 2);
  u16* ph1_bf    = (u16*)alloc((size_t)2048 * 256 * 2);
  u16* ph_bf     = (u16*)alloc((size_t)2048 * 256 * 2);
  u16* abig_bf   = (u16*)alloc((size_t)2048 * 256 * 2);
  u16* a_chunk   = (u16*)alloc((size_t)16384 * 512 * 2);
  u16* gi_all    = (u16*)alloc((size_t)65536 * 640 * 2);
  float* mrel32 = (float*)alloc((size_t)460 * 200 * 4);
  float* base32 = (float*)alloc((size_t)2048 * 460 * 4);
  float* qrel32 = (float*)alloc((size_t)2048 * 200 * 4);
  float* hout   = (float*)alloc((size_t)2048 * 200 * 4);
  float* ph32   = (float*)alloc((size_t)2048 * 200 * 4);
  float* gi2    = (float*)alloc((size_t)2048 * 600 * 4);
  float* ghg    = (float*)alloc((size_t)2048 * 600 * 4);
  float* gh2    = (float*)alloc((size_t)2048 * 200 * 4);
  float* al32   = (float*)alloc((size_t)10000 * 200 * 4);

  init_out<<<1, 64, 0, stream>>>(out);

  CvtTab tab;
  tab.t[0] = { r_emb,   re_bf,    460, 200,   512, 256 };
  tab.t[1] = { Wmap1,   wmap1_bf, 400, 200,   512, 256 };
  tab.t[2] = { Wmap2,   wmap2_bf, 200, 400,   256, 448 };
  tab.t[3] = { Wattn,   wattn_bf, 200, 200,   256, 256 };
  tab.t[4] = { Wih,     wih_bf,   600, 200,   640, 256 };
  tab.t[5] = { Whh,     whh_bf,   600, 200,   640, 256 };
  tab.t[6] = { Wh1,     wh1_bf,   200, 200,   256, 256 };
  tab.t[7] = { Wh2,     wh2_bf,   200, 200,   256, 256 };
  tab.t[8] = { Wal,     wal_bf,   200, 200,   256, 256 };
  tab.t[9] = { pre_emb, pre_bf, 10000, 256, 10112, 256 };
  tab.t[9] = { pre_emb, pre_bf, 10000, 200, 10112, 256 };
  cvt_all<<<dim3(512, 10), 256, 0, stream>>>(tab);

  gemm_bt<0,0><<<dim3(4, 4), 256, 0, stream>>>(re_bf, 256, wmap1_bf, 256, 200, 460, 400,
      bmap1, nullptr, hidden_bf, 512, nullptr, nullptr, nullptr);
  gemm_bt<0,0><<<dim3(2, 4), 256, 0, stream>>>(hidden_bf, 512, wmap2_bf, 448, 400, 460, 200,
      bmap2, mrel32, mrel_bf, 256, nullptr, nullptr, nullptr);
  gather_qrel<<<2048, 256, 0, stream>>>(mrel_bf, mrel32, trip, qrel_bf, qrel32);

  gemm_bt<0,0><<<dim3(2, 16), 256, 0, stream>>>(qrel_bf, 256, wattn_bf, 256, 200, 2048, 200,
      battn, nullptr, qa_bf, 256, nullptr, nullptr, nullptr);
  gemm_bt<0,0><<<dim3(4, 16), 256, 0, stream>>>(qa_bf, 256, mrel_bf, 256, 200, 2048, 460,
      nullptr, base32, nullptr, 0, nullptr, nullptr, nullptr);

  // M2T = Wih @ mapped_rel^T  (600 x 460)
  gemm_bt<0,0><<<dim3(4, 5), 256, 0, stream>>>(wih_bf, 256, mrel_bf, 256, 200, 600, 460,
      nullptr, nullptr, m2t_bf, 512, nullptr, nullptr, nullptr);

  for (int g = 0; g < 4; ++g){
    softmax_k<<<4096, 256, 0, stream>>>(part, base32, g * 8, a_chunk);
    gemm_bt<0,0><<<dim3(5, 128), 256, 0, stream>>>(a_chunk, 512, m2t_bf, 512, 460, 16384, 600,
        bih, nullptr, gi_all + (size_t)g * 16384 * 640, 640, nullptr, nullptr, nullptr);
  }

  gru_scan3<<<256, 512, 0, stream>>>(gi_all, whh_bf, bhh, cur_ts, hout);

  gemm_bt<0,0><<<dim3(2, 16), 256, 0, stream>>>(qrel_bf, 256, wh1_bf, 256, 200, 2048, 200,
      bh1, nullptr, ph1_bf, 256, nullptr, nullptr, nullptr);
  gemm_bt<1,0><<<dim3(2, 16), 256, 0, stream>>>(ph1_bf, 256, wh2_bf, 256, 200, 2048, 200,
      bh2, ph32, ph_bf, 256, qrel32, nullptr, nullptr);

  mloss<<<128, 256, 0, stream>>>(ph32, hout, out);

  gemm_bt<0,0><<<dim3(5, 16), 256, 0, stream>>>(qrel_bf, 256, wih_bf, 256, 200, 2048, 600,
      bih, gi2, nullptr, 0, nullptr, nullptr, nullptr);
  gemm_bt<0,0><<<dim3(5, 16), 256, 0, stream>>>(ph_bf, 256, whh_bf, 256, 200, 2048, 600,
      bhh, ghg, nullptr, 0, nullptr, nullptr, nullptr);
  gru_once<<<1600, 256, 0, stream>>>(gi2, ghg, ph32, gh2);

  u16* al_bf = a_chunk;
  gemm_bt<0,0><<<dim3(2, 79), 256, 0, stream>>>(pre_bf, 256, wal_bf, 256, 200, 10000, 200,
      bal, al32, al_bf, 256, nullptr, nullptr, nullptr);

  abig_k<<<2048, 256, 0, stream>>>(al32, gh2, trip, abig_bf);

  gemm_bt<2,1><<<dim3(79, 16), 256, 0, stream>>>(abig_bf, 256, al_bf, 256, 200, 2048, 10000,
      nullptr, out, nullptr, 0, nullptr, trip, out + 1);
}

// Round 5
// 503.075 us; speedup vs baseline: 1.7746x; 1.0206x over previous
//
#include <hip/hip_runtime.h>
#include <cstdint>
#include <cstddef>

typedef unsigned short u16;
typedef __attribute__((ext_vector_type(8))) short short8;
typedef __attribute__((ext_vector_type(4))) float f32x4;

__device__ __forceinline__ f32x4 mfma16(short8 a, short8 b, f32x4 c){
  return __builtin_amdgcn_mfma_f32_16x16x32_bf16(a, b, c, 0, 0, 0);
}
__device__ __forceinline__ float bf2f(u16 u){
  unsigned v = ((unsigned)u) << 16; float f; __builtin_memcpy(&f, &v, 4); return f;
}
__device__ __forceinline__ u16 f2bf(float f){
  unsigned u; __builtin_memcpy(&u, &f, 4);
  u += 0x7FFFu + ((u >> 16) & 1u);
  return (u16)(u >> 16);
}
__device__ __forceinline__ float sigf(float x){ return 1.f / (1.f + __expf(-x)); }

// ---------------- fp32 -> zero-padded bf16 conversion ----------------
struct CvtD { const float* s; u16* d; int M, K, Mp, Kp; };
struct CvtTab { CvtD t[10]; };

__global__ void cvt_all(CvtTab tab){
  CvtD de = tab.t[blockIdx.y];
  int total = de.Mp * de.Kp;
  for (int i = blockIdx.x * blockDim.x + threadIdx.x; i < total; i += gridDim.x * blockDim.x){
    int r = i / de.Kp, c = i - r * de.Kp;
    float v = (r < de.M && c < de.K) ? de.s[(size_t)r * de.K + c] : 0.f;
    de.d[i] = f2bf(v);
  }
}

__global__ void init_out(float* o){ if (threadIdx.x < 2) o[threadIdx.x] = 0.f; }

// q_rel gather
__global__ void gather_qrel(const u16* __restrict__ mbf, const float* __restrict__ m32,
                            const int* __restrict__ trip, u16* __restrict__ qbf,
                            float* __restrict__ q32){
  int i = blockIdx.x * blockDim.x + threadIdx.x;
  if (i < 2048 * 256){
    int b = i >> 8, c = i & 255;
    int rel = trip[b * 3 + 1];
    qbf[i] = mbf[rel * 256 + c];
    if (c < 200) q32[b * 200 + c] = m32[rel * 200 + c];
  }
}

// ---------------- generic MFMA GEMM (2-phase counted-vmcnt pipeline) ----------------
// C = A(M,K) @ B(N,K)^T + bias, 128x128 tile, BK=64 double-buffered.
template<int MODE, int GROUP>
__global__ __launch_bounds__(256) void gemm_bt(
    const u16* __restrict__ A, int lda,
    const u16* __restrict__ B, int ldb,
    int K, int Mreal, int Nreal,
    const float* __restrict__ bias,
    float* __restrict__ C32,
    u16* __restrict__ C16, int ldc16,
    const float* __restrict__ extra,
    const int* __restrict__ trip,
    float* __restrict__ loss)
{
  __shared__ u16 As[2][128 * 64];
  __shared__ u16 Bs[2][128 * 64];
  __shared__ float red[256];
  const int tid = threadIdx.x;
  const int wave = tid >> 6, lane = tid & 63;

  const int gx = gridDim.x, gy = gridDim.y;
  const int nwg = gx * gy;
  int orig = blockIdx.y * gx + blockIdx.x;
  int q = nwg >> 3, r8 = nwg & 7;
  int xcd = orig & 7, idx = orig >> 3;
  int fid = (xcd < r8 ? xcd * (q + 1) : r8 * (q + 1) + (xcd - r8) * q) + idx;
  int mx, my;
  if (GROUP == 0){ my = fid / gx; mx = fid - my * gx; }
  else           { mx = fid / gy; my = fid - mx * gy; }

  const int m0 = my * 128, n0 = mx * 128;
  const int wm = (wave >> 1) * 64, wn = (wave & 1) * 64;
  const int lr = lane >> 3, lc = (lane & 7) * 8;
  const int fr = lane & 15, fk = (lane >> 4) * 8;

  f32x4 acc[4][4];
  #pragma unroll
  for (int i = 0; i < 4; ++i)
    #pragma unroll
    for (int j = 0; j < 4; ++j) acc[i][j] = (f32x4){0.f, 0.f, 0.f, 0.f};

  const int kT = (K + 63) >> 6;

  // stage tile kt into buffer p (8 global_load_lds per wave)
  auto STAGE = [&](int kt, int p){
    #pragma unroll
    for (int i = 0; i < 4; ++i){
      int ch = wave * 4 + i;
      const u16* ga = A + (size_t)(m0 + ch * 8 + lr) * lda + kt * 64 + lc;
      __builtin_amdgcn_global_load_lds((const __attribute__((address_space(1))) void*)ga,
          (__attribute__((address_space(3))) void*)(&As[p][0] + ch * 512), 16, 0, 0);
      const u16* gb = B + (size_t)(n0 + ch * 8 + lr) * ldb + kt * 64 + lc;
      __builtin_amdgcn_global_load_lds((const __attribute__((address_space(1))) void*)gb,
          (__attribute__((address_space(3))) void*)(&Bs[p][0] + ch * 512), 16, 0, 0);
    }
  };

  STAGE(0, 0);
  for (int kt = 0; kt < kT; ++kt){
    const int p = kt & 1;
    if (kt + 1 < kT){
      STAGE(kt + 1, p ^ 1);
      // wait only for tile-kt's 8 loads (next tile's 8 stay in flight)
      __builtin_amdgcn_sched_barrier(0);
      asm volatile("s_waitcnt vmcnt(8)" ::: "memory");
    } else {
      __builtin_amdgcn_sched_barrier(0);
      asm volatile("s_waitcnt vmcnt(0)" ::: "memory");
    }
    __builtin_amdgcn_sched_barrier(0);
    __builtin_amdgcn_s_barrier();        // tile kt visible to all waves
    __builtin_amdgcn_sched_barrier(0);

    #pragma unroll
    for (int ks = 0; ks < 2; ++ks){
      short8 av[4], bv[4];
      #pragma unroll
      for (int i = 0; i < 4; ++i){
        av[i] = *(const short8*)(&As[p][0] + (wm + i * 16 + fr) * 64 + ks * 32 + fk);
        bv[i] = *(const short8*)(&Bs[p][0] + (wn + i * 16 + fr) * 64 + ks * 32 + fk);
      }
      #pragma unroll
      for (int i = 0; i < 4; ++i)
        #pragma unroll
        for (int j = 0; j < 4; ++j)
          acc[i][j] = mfma16(av[i], bv[j], acc[i][j]);
    }
    // per-wave ds_reads drained, then barrier: next iter may overwrite buf p^1
    __builtin_amdgcn_sched_barrier(0);
    asm volatile("s_waitcnt lgkmcnt(0)" ::: "memory");
    __builtin_amdgcn_sched_barrier(0);
    __builtin_amdgcn_s_barrier();
    __builtin_amdgcn_sched_barrier(0);
  }

  if (MODE == 2){
    float lsum = 0.f;
    #pragma unroll
    for (int i = 0; i < 4; ++i){
      #pragma unroll
      for (int r = 0; r < 4; ++r){
        int row = m0 + wm + i * 16 + (lane >> 4) * 4 + r;
        int tcol = trip[row * 3 + 2];
        #pragma unroll
        for (int j = 0; j < 4; ++j){
          int col = n0 + wn + j * 16 + fr;
          if (col < Nreal){
            float v = acc[i][j][r];
            float e = __expf(-fabsf(v));
            float inv = __builtin_amdgcn_rcpf(1.f + e);
            C32[2 + (size_t)row * Nreal + col] = (v >= 0.f) ? inv : e * inv;
            float x = (tcol == col) ? v : -v;
            lsum += fminf(x, 0.f) - __logf(1.f + e);
          }
        }
      }
    }
    red[tid] = lsum;
    __syncthreads();
    for (int s = 128; s > 0; s >>= 1){
      if (tid < s) red[tid] += red[tid + s];
      __syncthreads();
    }
    if (tid == 0) atomicAdd(loss, -red[0] * (1.f / 20480000.f));
    return;
  }

  #pragma unroll
  for (int i = 0; i < 4; ++i){
    #pragma unroll
    for (int j = 0; j < 4; ++j){
      int col = n0 + wn + j * 16 + fr;
      float bvl = 0.f;
      if (bias && col < Nreal) bvl = bias[col];
      #pragma unroll
      for (int r = 0; r < 4; ++r){
        int row = m0 + wm + i * 16 + (lane >> 4) * 4 + r;
        float v = acc[i][j][r] + bvl;
        if (MODE == 0){
          if (C32 && row < Mreal && col < Nreal) C32[(size_t)row * Nreal + col] = v;
          if (C16) C16[(size_t)row * ldc16 + col] =
              (row < Mreal && col < Nreal) ? f2bf(v) : (u16)0;
        } else {
          if (row < Mreal){
            if (col < Nreal){
              float pv = 0.1f * v + extra[(size_t)row * Nreal + col];
              C32[(size_t)row * Nreal + col] = pv;
              C16[(size_t)row * ldc16 + col] = f2bf(pv);
            } else {
              C16[(size_t)row * ldc16 + col] = 0;
            }
          }
        }
      }
    }
  }
}

// ---------------- masked softmax over R=460 ----------------
__global__ __launch_bounds__(256) void softmax_k(
    const float* __restrict__ part, const float* __restrict__ base,
    int t0, u16* __restrict__ aout)
{
  int wave = threadIdx.x >> 6, lane = threadIdx.x & 63;
  int idx = blockIdx.x * 4 + wave;
  int tl = idx >> 11, b = idx & 2047;
  int t = t0 + tl;
  const float* pr = part + (size_t)b * 14720 + t * 460;
  const float* br = base + (size_t)b * 460;
  int r0 = lane * 8;
  float vals[8];
  if (lane < 57){
    float4 pa = *(const float4*)(pr + r0);
    float4 pb = *(const float4*)(pr + r0 + 4);
    float4 ba = *(const float4*)(br + r0);
    float4 bb = *(const float4*)(br + r0 + 4);
    float pv[8] = {pa.x, pa.y, pa.z, pa.w, pb.x, pb.y, pb.z, pb.w};
    float bw[8] = {ba.x, ba.y, ba.z, ba.w, bb.x, bb.y, bb.z, bb.w};
    #pragma unroll
    for (int u = 0; u < 8; ++u){
      float a = pv[u] * bw[u];
      bool valid = (r0 + u) < 460;
      vals[u] = (!valid) ? -__builtin_inff() : ((a == 0.f) ? -1000000000.0f : a);
    }
  } else {
    #pragma unroll
    for (int u = 0; u < 8; ++u){
      int r = r0 + u;
      if (r < 460){
        float a = pr[r] * br[r];
        vals[u] = (a == 0.f) ? -1000000000.0f : a;
      } else vals[u] = -__builtin_inff();
    }
  }
  float m = vals[0];
  #pragma unroll
  for (int u = 1; u < 8; ++u) m = fmaxf(m, vals[u]);
  #pragma unroll
  for (int s = 1; s < 64; s <<= 1) m = fmaxf(m, __shfl_xor(m, s));
  float e[8]; float sum = 0.f;
  #pragma unroll
  for (int u = 0; u < 8; ++u){
    float x = vals[u];
    float ev = (x == -__builtin_inff()) ? 0.f : __expf(x - m);
    e[u] = ev; sum += ev;
  }
  #pragma unroll
  for (int s = 1; s < 64; s <<= 1) sum += __shfl_xor(sum, s);
  float inv = __builtin_amdgcn_rcpf(sum);
  union { u16 o[8]; uint4 v; } pk;
  #pragma unroll
  for (int u = 0; u < 8; ++u) pk.o[u] = f2bf(e[u] * inv);
  *(uint4*)(aout + (size_t)idx * 512 + r0) = pk.v;
}

// ---------------- GRU recurrence v3: 256 blocks x 8 rows x 8 waves ------------------
__global__ __launch_bounds__(512, 2) void gru_scan3(
    const u16* __restrict__ gi_all,
    const u16* __restrict__ Whh,
    const float* __restrict__ bhh,
    const int* __restrict__ cur_ts,
    float* __restrict__ hout)
{
  __shared__ u16 hbf[16 * 256];
  __shared__ float hf[8 * 200];
  __shared__ float ghs[8][648];
  __shared__ u16 gis[2][8 * 640];
  __shared__ float bhs[600];
  __shared__ int cts[8];
  const int tid = threadIdx.x, wave = tid >> 6, lane = tid & 63;
  const int rb = blockIdx.x * 8;
  const int fr = lane & 15, fkg = lane >> 4;
  const int fk = fkg * 8;

  for (int i = tid; i < 16 * 256; i += 512) hbf[i] = 0;
  for (int i = tid; i < 8 * 200; i += 512) hf[i] = 0.f;
  for (int i = tid; i < 600; i += 512) bhs[i] = bhh[i];
  if (tid < 8) cts[tid] = cur_ts[rb + tid];
  __syncthreads();
  int Trun = 0;
  #pragma unroll
  for (int r = 0; r < 8; ++r) Trun = max(Trun, cts[r]);

  short8 wb[5][7];
  #pragma unroll
  for (int f = 0; f < 5; ++f)
    #pragma unroll
    for (int ks = 0; ks < 7; ++ks)
      wb[f][ks] = *(const short8*)(Whh + (size_t)(wave * 80 + f * 16 + fr) * 256 + ks * 32 + fk);

  if (Trun > 0){
    const u16* src = gi_all + (size_t)rb * 640;
    __builtin_amdgcn_global_load_lds(
        (const __attribute__((address_space(1))) void*)(src + tid * 8),
        (__attribute__((address_space(3))) void*)(&gis[0][0] + tid * 8), 16, 0, 0);
    if (tid < 128)
      __builtin_amdgcn_global_load_lds(
          (const __attribute__((address_space(1))) void*)(src + (512 + tid) * 8),
          (__attribute__((address_space(3))) void*)(&gis[0][0] + (512 + tid) * 8), 16, 0, 0);
  }
  __syncthreads();

  const int grow = wave;
  const int crow = (Trun > 0) ? cts[grow] : 0;

  for (int t = 0; t < Trun; ++t){
    f32x4 acc[5];
    #pragma unroll
    for (int f = 0; f < 5; ++f) acc[f] = (f32x4){0.f, 0.f, 0.f, 0.f};
    #pragma unroll
    for (int ks = 0; ks < 7; ++ks){
      short8 av = *(const short8*)(hbf + ((fr * 256 + ks * 32 + fk) ^ ((fr & 7) << 3)));
      #pragma unroll
      for (int f = 0; f < 5; ++f)
        acc[f] = mfma16(av, wb[f][ks], acc[f]);
    }
    if (fkg < 2){
      #pragma unroll
      for (int f = 0; f < 5; ++f){
        int col = wave * 80 + f * 16 + fr;
        #pragma unroll
        for (int r = 0; r < 4; ++r)
          ghs[fkg * 4 + r][col] = acc[f][r];
      }
    }
    __builtin_amdgcn_sched_barrier(0);
    asm volatile("s_waitcnt vmcnt(0) lgkmcnt(0)" ::: "memory");
    __builtin_amdgcn_sched_barrier(0);
    __builtin_amdgcn_s_barrier();
    __builtin_amdgcn_sched_barrier(0);

    if (t + 1 < Trun){
      const u16* src = gi_all + ((size_t)(t + 1) * 2048 + rb) * 640;
      u16* dst = &gis[(t + 1) & 1][0];
      __builtin_amdgcn_global_load_lds(
          (const __attribute__((address_space(1))) void*)(src + tid * 8),
          (__attribute__((address_space(3))) void*)(dst + tid * 8), 16, 0, 0);
      if (tid < 128)
        __builtin_amdgcn_global_load_lds(
            (const __attribute__((address_space(1))) void*)(src + (512 + tid) * 8),
            (__attribute__((address_space(3))) void*)(dst + (512 + tid) * 8), 16, 0, 0);
    }

    if (t < crow){
      const u16* gr = &gis[t & 1][0] + grow * 640;
      #pragma unroll
      for (int k = 0; k < 4; ++k){
        int d = lane + 64 * k;
        if (d < 200){
          float i0 = bf2f(gr[d]);
          float i1 = bf2f(gr[200 + d]);
          float i2 = bf2f(gr[400 + d]);
          float g0 = ghs[grow][d] + bhs[d];
          float g1 = ghs[grow][200 + d] + bhs[200 + d];
          float g2 = ghs[grow][400 + d] + bhs[400 + d];
          float e0 = __expf(-(i0 + g0));
          float r_ = __builtin_amdgcn_rcpf(1.f + e0);
          float e1 = __expf(-(i1 + g1));
          float z  = __builtin_amdgcn_rcpf(1.f + e1);
          float xn = i2 + r_ * g2;
          float e2 = __expf(2.f * xn);
          float n_ = 1.f - 2.f * __builtin_amdgcn_rcpf(e2 + 1.f);
          float hn = (1.f - z) * n_ + z * hf[grow * 200 + d];
          hf[grow * 200 + d] = hn;
          hbf[(grow * 256 + d) ^ (grow << 3)] = f2bf(hn);
        }
      }
    }
    __builtin_amdgcn_sched_barrier(0);
    asm volatile("s_waitcnt lgkmcnt(0)" ::: "memory");
    __builtin_amdgcn_sched_barrier(0);
    __builtin_amdgcn_s_barrier();
    __builtin_amdgcn_sched_barrier(0);
  }

  for (int i = tid; i < 1600; i += 512){
    int row = i / 200, d = i - row * 200;
    hout[(size_t)(rb + row) * 200 + d] = hf[row * 200 + d];
  }
}

// ---------------- match_loss ----------------
__global__ __launch_bounds__(256) void mloss(const float* __restrict__ a,
                                             const float* __restrict__ b,
                                             float* __restrict__ o){
  __shared__ float red[256];
  float s = 0.f;
  for (int i = blockIdx.x * 256 + threadIdx.x; i < 409600; i += gridDim.x * 256){
    float d = a[i] - b[i]; s += d * d;
  }
  red[threadIdx.x] = s; __syncthreads();
  for (int t = 128; t > 0; t >>= 1){
    if (threadIdx.x < t) red[threadIdx.x] += red[threadIdx.x + t];
    __syncthreads();
  }
  if (threadIdx.x == 0) atomicAdd(o, red[0] * (1.f / 409600.f));
}

// ---------------- gh = GRU(q_rel, predicted_hist) gate combine ----------------
__global__ __launch_bounds__(256) void gru_once(const float* __restrict__ gi,
                                                const float* __restrict__ gg,
                                                const float* __restrict__ hprev,
                                                float* __restrict__ outp){
  int i = blockIdx.x * 256 + threadIdx.x;
  if (i < 409600){
    int b = i / 200, d = i - b * 200;
    float i0 = gi[b * 600 + d], i1 = gi[b * 600 + 200 + d], i2 = gi[b * 600 + 400 + d];
    float g0 = gg[b * 600 + d], g1 = gg[b * 600 + 200 + d], g2 = gg[b * 600 + 400 + d];
    float r = sigf(i0 + g0);
    float z = sigf(i1 + g1);
    float n = tanhf(i2 + r * g2);
    outp[i] = (1.f - z) * n + z * hprev[i];
  }
}

// ---------------- A_big = (aligned_sub * gh) as bf16 ----------------
__global__ __launch_bounds__(256) void abig_k(const float* __restrict__ al32,
                                              const float* __restrict__ gh2,
                                              const int* __restrict__ trip,
                                              u16* __restrict__ abig){
  int i = blockIdx.x * 256 + threadIdx.x;
  if (i < 2048 * 256){
    int b = i >> 8, c = i & 255;
    float v = 0.f;
    if (c < 200){
      int sub = trip[b * 3 + 0];
      v = al32[(size_t)sub * 200 + c] * gh2[b * 200 + c];
    }
    abig[i] = f2bf(v);
  }
}

// =====================================================================================
extern "C" void kernel_launch(void* const* d_in, const int* in_sizes, int n_in,
                              void* d_out, int out_size, void* d_ws, size_t ws_size,
                              hipStream_t stream)
{
  (void)in_sizes; (void)n_in; (void)out_size; (void)ws_size;
  const float* pre_emb = (const float*)d_in[0];
  const float* r_emb   = (const float*)d_in[1];
  const int*   trip    = (const int*)d_in[2];
  const float* part    = (const float*)d_in[3];
  const int*   cur_ts  = (const int*)d_in[4];
  const float* Wmap1 = (const float*)d_in[5];   const float* bmap1 = (const float*)d_in[6];
  const float* Wmap2 = (const float*)d_in[7];   const float* bmap2 = (const float*)d_in[8];
  const float* Wattn = (const float*)d_in[9];   const float* battn = (const float*)d_in[10];
  const float* Wih   = (const float*)d_in[11];  const float* Whh   = (const float*)d_in[12];
  const float* bih   = (const float*)d_in[13];  const float* bhh   = (const float*)d_in[14];
  const float* Wh1   = (const float*)d_in[15];  const float* bh1   = (const float*)d_in[16];
  const float* Wh2   = (const float*)d_in[17];  const float* bh2   = (const float*)d_in[18];
  const float* Wal   = (const float*)d_in[19];  const float* bal   = (const float*)d_in[20];
  float* out = (float*)d_out;

  char* wsb = (char*)d_ws;
  size_t off = 0;
  auto alloc = [&](size_t bytes) -> void* {
    void* p = wsb + off;
    off = (off + bytes + 255) & ~(size_t)255;
    return p;
  };
  u16* re_bf     = (u16*)alloc((size_t)512 * 256 * 2);
  u16* wmap1_bf  = (u16*)alloc((size_t)512 * 256 * 2);
  u16* wmap2_bf  = (u16*)alloc((size_t)256 * 448 * 2);
  u16* wattn_bf  = (u16*)alloc((size_t)256 * 256 * 2);
  u16* wih_bf    = (u16*)alloc((size_t)640 * 256 * 2);
  u16* whh_bf    = (u16*)alloc((size_t)640 * 256 * 2);
  u16* wh1_bf    = (u16*)alloc((size_t)256 * 256 * 2);
  u16* wh2_bf    = (u16*)alloc((size_t)256 * 256 * 2);
  u16* wal_bf    = (u16*)alloc((size_t)256 * 256 * 2);
  u16* pre_bf    = (u16*)alloc((size_t)10112 * 256 * 2);
  u16* hidden_bf = (u16*)alloc((size_t)512 * 512 * 2);
  u16* mrel_bf   = (u16*)alloc((size_t)512 * 256 * 2);
  u16* m2t_bf    = (u16*)alloc((size_t)640 * 512 * 2);
  u16* qrel_bf   = (u16*)alloc((size_t)2048 * 256 * 2);
  u16* qa_bf     = (u16*)alloc((size_t)2048 * 256 * 2);
  u16* ph1_bf    = (u16*)alloc((size_t)2048 * 256 * 2);
  u16* ph_bf     = (u16*)alloc((size_t)2048 * 256 * 2);
  u16* abig_bf   = (u16*)alloc((size_t)2048 * 256 * 2);
  u16* a_chunk   = (u16*)alloc((size_t)16384 * 512 * 2);
  u16* gi_all    = (u16*)alloc((size_t)65536 * 640 * 2);
  float* mrel32 = (float*)alloc((size_t)460 * 200 * 4);
  float* base32 = (float*)alloc((size_t)2048 * 460 * 4);
  float* qrel32 = (float*)alloc((size_t)2048 * 200 * 4);
  float* hout   = (float*)alloc((size_t)2048 * 200 * 4);
  float* ph32   = (float*)alloc((size_t)2048 * 200 * 4);
  float* gi2    = (float*)alloc((size_t)2048 * 600 * 4);
  float* ghg    = (float*)alloc((size_t)2048 * 600 * 4);
  float* gh2    = (float*)alloc((size_t)2048 * 200 * 4);
  float* al32   = (float*)alloc((size_t)10000 * 200 * 4);

  init_out<<<1, 64, 0, stream>>>(out);

  CvtTab tab;
  tab.t[0] = { r_emb,   re_bf,    460, 200,   512, 256 };
  tab.t[1] = { Wmap1,   wmap1_bf, 400, 200,   512, 256 };
  tab.t[2] = { Wmap2,   wmap2_bf, 200, 400,   256, 448 };
  tab.t[3] = { Wattn,   wattn_bf, 200, 200,   256, 256 };
  tab.t[4] = { Wih,     wih_bf,   600, 200,   640, 256 };
  tab.t[5] = { Whh,     whh_bf,   600, 200,   640, 256 };
  tab.t[6] = { Wh1,     wh1_bf,   200, 200,   256, 256 };
  tab.t[7] = { Wh2,     wh2_bf,   200, 200,   256, 256 };
  tab.t[8] = { Wal,     wal_bf,   200, 200,   256, 256 };
  tab.t[9] = { pre_emb, pre_bf, 10000, 200, 10112, 256 };
  cvt_all<<<dim3(512, 10), 256, 0, stream>>>(tab);

  gemm_bt<0,0><<<dim3(4, 4), 256, 0, stream>>>(re_bf, 256, wmap1_bf, 256, 200, 460, 400,
      bmap1, nullptr, hidden_bf, 512, nullptr, nullptr, nullptr);
  gemm_bt<0,0><<<dim3(2, 4), 256, 0, stream>>>(hidden_bf, 512, wmap2_bf, 448, 400, 460, 200,
      bmap2, mrel32, mrel_bf, 256, nullptr, nullptr, nullptr);
  gather_qrel<<<2048, 256, 0, stream>>>(mrel_bf, mrel32, trip, qrel_bf, qrel32);

  gemm_bt<0,0><<<dim3(2, 16), 256, 0, stream>>>(qrel_bf, 256, wattn_bf, 256, 200, 2048, 200,
      battn, nullptr, qa_bf, 256, nullptr, nullptr, nullptr);
  gemm_bt<0,0><<<dim3(4, 16), 256, 0, stream>>>(qa_bf, 256, mrel_bf, 256, 200, 2048, 460,
      nullptr, base32, nullptr, 0, nullptr, nullptr, nullptr);

  // M2T = Wih @ mapped_rel^T  (600 x 460)
  gemm_bt<0,0><<<dim3(4, 5), 256, 0, stream>>>(wih_bf, 256, mrel_bf, 256, 200, 600, 460,
      nullptr, nullptr, m2t_bf, 512, nullptr, nullptr, nullptr);

  for (int g = 0; g < 4; ++g){
    softmax_k<<<4096, 256, 0, stream>>>(part, base32, g * 8, a_chunk);
    gemm_bt<0,0><<<dim3(5, 128), 256, 0, stream>>>(a_chunk, 512, m2t_bf, 512, 460, 16384, 600,
        bih, nullptr, gi_all + (size_t)g * 16384 * 640, 640, nullptr, nullptr, nullptr);
  }

  gru_scan3<<<256, 512, 0, stream>>>(gi_all, whh_bf, bhh, cur_ts, hout);

  gemm_bt<0,0><<<dim3(2, 16), 256, 0, stream>>>(qrel_bf, 256, wh1_bf, 256, 200, 2048, 200,
      bh1, nullptr, ph1_bf, 256, nullptr, nullptr, nullptr);
  gemm_bt<1,0><<<dim3(2, 16), 256, 0, stream>>>(ph1_bf, 256, wh2_bf, 256, 200, 2048, 200,
      bh2, ph32, ph_bf, 256, qrel32, nullptr, nullptr);

  mloss<<<128, 256, 0, stream>>>(ph32, hout, out);

  gemm_bt<0,0><<<dim3(5, 16), 256, 0, stream>>>(qrel_bf, 256, wih_bf, 256, 200, 2048, 600,
      bih, gi2, nullptr, 0, nullptr, nullptr, nullptr);
  gemm_bt<0,0><<<dim3(5, 16), 256, 0, stream>>>(ph_bf, 256, whh_bf, 256, 200, 2048, 600,
      bhh, ghg, nullptr, 0, nullptr, nullptr, nullptr);
  gru_once<<<1600, 256, 0, stream>>>(gi2, ghg, ph32, gh2);

  u16* al_bf = a_chunk;
  gemm_bt<0,0><<<dim3(2, 79), 256, 0, stream>>>(pre_bf, 256, wal_bf, 256, 200, 10000, 200,
      bal, al32, al_bf, 256, nullptr, nullptr, nullptr);

  abig_k<<<2048, 256, 0, stream>>>(al32, gh2, trip, abig_bf);

  gemm_bt<2,1><<<dim3(79, 16), 256, 0, stream>>>(abig_bf, 256, al_bf, 256, 200, 2048, 10000,
      nullptr, out, nullptr, 0, nullptr, trip, out + 1);
}